// Round 3
// baseline (473.312 us; speedup 1.0000x reference)
//
#include <hip/hip_runtime.h>
#include <hip/hip_bf16.h>

typedef __hip_bfloat16 bf16;
typedef __bf16 bf16x8 __attribute__((ext_vector_type(8)));
typedef float f32x4 __attribute__((ext_vector_type(4)));

// async global->LDS, 16B per lane. LDS dest = wave-uniform base + lane*16.
__device__ __forceinline__ void async16(void* lds_base, const void* g) {
  __builtin_amdgcn_global_load_lds(
      (const __attribute__((address_space(1))) void*)g,
      (__attribute__((address_space(3))) void*)lds_base, 16, 0, 0);
}

// ---------------------------------------------------------------------------
// f32 -> bf16 flat convert (weights)
// ---------------------------------------------------------------------------
__global__ void cvt_bf16_kernel(const float* __restrict__ s, bf16* __restrict__ d, int n4) {
  const int i = blockIdx.x * 256 + threadIdx.x;
  if (i >= n4) return;
  const float4 v = ((const float4*)s)[i];
  bf16 h0 = __float2bfloat16(v.x), h1 = __float2bfloat16(v.y);
  bf16 h2 = __float2bfloat16(v.z), h3 = __float2bfloat16(v.w);
  ushort4 o;
  o.x = *(unsigned short*)&h0; o.y = *(unsigned short*)&h1;
  o.z = *(unsigned short*)&h2; o.w = *(unsigned short*)&h3;
  *(ushort4*)((unsigned short*)d + (size_t)i * 4) = o;
}

// f32 [2048][2048] -> bf16 into rows of stride 4096 (for [Wog|Wig] K-merge)
__global__ void cvt_bf16_strided(const float* __restrict__ s, bf16* __restrict__ d, int n4) {
  const int i = blockIdx.x * 256 + threadIdx.x;
  if (i >= n4) return;
  const int row = i >> 9;          // 512 float4 per 2048-col row
  const int col4 = i & 511;
  const float4 v = ((const float4*)s)[i];
  bf16 h0 = __float2bfloat16(v.x), h1 = __float2bfloat16(v.y);
  bf16 h2 = __float2bfloat16(v.z), h3 = __float2bfloat16(v.w);
  ushort4 o;
  o.x = *(unsigned short*)&h0; o.y = *(unsigned short*)&h1;
  o.z = *(unsigned short*)&h2; o.w = *(unsigned short*)&h3;
  *(ushort4*)((unsigned short*)d + (size_t)row * 4096 + col4 * 4) = o;
}

// ---------------------------------------------------------------------------
// x (B,L,H) fp32 -> comb[.., 2048..4095] bf16 (A-matrix K-merge half)
//                 + xbT (B,H,L) bf16 (for GLA V-frags). Vectorized 16B/8B.
// ---------------------------------------------------------------------------
__global__ __launch_bounds__(256) void convert_x_kernel(
    const float* __restrict__ x, bf16* __restrict__ comb, bf16* __restrict__ xbT) {
  __shared__ float tile[64][65];
  const int b = blockIdx.z;
  const int l0 = blockIdx.x * 64, d0 = blockIdx.y * 64;
  const int t = threadIdx.x;
  const int c4 = (t & 15) * 4, r = t >> 4;  // r 0..15
  const size_t base = ((size_t)b * 4096 + l0) * 2048 + d0;
#pragma unroll
  for (int i = 0; i < 4; ++i) {
    const int row = i * 16 + r;
    const float4 v = *(const float4*)(x + base + (size_t)row * 2048 + c4);
    tile[row][c4 + 0] = v.x; tile[row][c4 + 1] = v.y;
    tile[row][c4 + 2] = v.z; tile[row][c4 + 3] = v.w;
    bf16 h0 = __float2bfloat16(v.x), h1 = __float2bfloat16(v.y);
    bf16 h2 = __float2bfloat16(v.z), h3 = __float2bfloat16(v.w);
    ushort4 o;
    o.x = *(unsigned short*)&h0; o.y = *(unsigned short*)&h1;
    o.z = *(unsigned short*)&h2; o.w = *(unsigned short*)&h3;
    *(ushort4*)(comb + ((size_t)(b * 4096 + l0 + row)) * 4096 + 2048 + d0 + c4) = o;
  }
  __syncthreads();
#pragma unroll
  for (int i = 0; i < 4; ++i) {
    const int d = i * 16 + r;
    bf16 h0 = __float2bfloat16(tile[c4 + 0][d]);
    bf16 h1 = __float2bfloat16(tile[c4 + 1][d]);
    bf16 h2 = __float2bfloat16(tile[c4 + 2][d]);
    bf16 h3 = __float2bfloat16(tile[c4 + 3][d]);
    ushort4 o;
    o.x = *(unsigned short*)&h0; o.y = *(unsigned short*)&h1;
    o.z = *(unsigned short*)&h2; o.w = *(unsigned short*)&h3;
    *(ushort4*)(xbT + ((size_t)(b * 2048 + d0 + d)) * 4096 + l0 + c4) = o;
  }
}

// ---------------------------------------------------------------------------
// m97-style bf16 GEMM for the small logits GEMM (N=256). lda-strided A.
// C[m,n] = sum_k A[m,k]*B[n,k]; 128x128 tile, BK=32, 256 thr, 16x16x32 MFMA.
// ---------------------------------------------------------------------------
__global__ __launch_bounds__(256, 2) void gemm_logits(
    const bf16* __restrict__ A, const bf16* __restrict__ B,
    float* __restrict__ outf, int lda, int N, int K) {
  __shared__ bf16 lA[128 * 32];
  __shared__ bf16 lB[128 * 32];
  const int tid = threadIdx.x;
  const int lane = tid & 63, wave = tid >> 6;
  const int l15 = lane & 15, l4 = lane >> 4;
  const int bm = blockIdx.x * 128, bn = blockIdx.y * 128;
  const int wm = (wave & 1) * 64, wn = (wave >> 1) * 64;
  const int srow = tid >> 2;
  const int skc = (tid & 3) * 8;

  const f32x4 fz = {0.f, 0.f, 0.f, 0.f};
  f32x4 acc[4][4];
#pragma unroll
  for (int i = 0; i < 4; ++i)
#pragma unroll
    for (int j = 0; j < 4; ++j) acc[i][j] = fz;

  bf16* lAu  = lA + wave * 512;
  bf16* lAu2 = lA + 2048 + wave * 512;
  bf16* lBu  = lB + wave * 512;
  bf16* lBu2 = lB + 2048 + wave * 512;

  const bf16* gA0 = A + (size_t)(bm + srow) * lda + skc;
  const bf16* gA1 = A + (size_t)(bm + srow + 64) * lda + skc;
  const bf16* gB0 = B + (size_t)(bn + srow) * K + skc;
  const bf16* gB1 = B + (size_t)(bn + srow + 64) * K + skc;
  for (int k0 = 0; k0 < K; k0 += 32) {
    __syncthreads();
    async16(lAu, gA0 + k0);
    async16(lAu2, gA1 + k0);
    async16(lBu, gB0 + k0);
    async16(lBu2, gB1 + k0);
    __syncthreads();
    bf16x8 af[4], bfv[4];
#pragma unroll
    for (int mt = 0; mt < 4; ++mt)
      af[mt] = *(const bf16x8*)(lA + (wm + mt * 16 + l15) * 32 + l4 * 8);
#pragma unroll
    for (int nt = 0; nt < 4; ++nt)
      bfv[nt] = *(const bf16x8*)(lB + (wn + nt * 16 + l15) * 32 + l4 * 8);
#pragma unroll
    for (int mt = 0; mt < 4; ++mt)
#pragma unroll
      for (int nt = 0; nt < 4; ++nt)
        acc[mt][nt] = __builtin_amdgcn_mfma_f32_16x16x32_bf16(af[mt], bfv[nt], acc[mt][nt], 0, 0, 0);
  }

#pragma unroll
  for (int mt = 0; mt < 4; ++mt)
#pragma unroll
    for (int r = 0; r < 4; ++r) {
      const int gr = bm + wm + mt * 16 + l4 * 4 + r;
#pragma unroll
      for (int nt = 0; nt < 4; ++nt) {
        const int gc = bn + wn + nt * 16 + l15;
        outf[(size_t)gr * N + gc] = acc[mt][nt][r];
      }
    }
}

// ---------------------------------------------------------------------------
// 256x256-tile 8-phase bf16 GEMM, single source, K = 64*NT (2048 or 4096).
// T1 XCD-swizzle + T2 LDS XOR-swizzle + T3/T4 counted-vmcnt + T5 setprio.
// MODE 1: RMSNorm-gate-swish epilogue -> bf16.  MODE 2: fp32 out.
// 512 threads = 8 waves (2M x 4N); per-wave out 128x64; BK=64; LDS 128 KiB.
// ---------------------------------------------------------------------------
#define QMFMA(AF, BF, MH, NH)                                               \
  do {                                                                      \
    __builtin_amdgcn_s_setprio(1);                                          \
    _Pragma("unroll") for (int ks_ = 0; ks_ < 2; ++ks_) {                   \
      _Pragma("unroll") for (int mt_ = 0; mt_ < 4; ++mt_) {                 \
        _Pragma("unroll") for (int nt_ = 0; nt_ < 2; ++nt_)                 \
            acc[(MH) * 4 + mt_][(NH) * 2 + nt_] =                           \
                __builtin_amdgcn_mfma_f32_16x16x32_bf16(                    \
                    AF[mt_][ks_], BF[nt_][ks_],                             \
                    acc[(MH) * 4 + mt_][(NH) * 2 + nt_], 0, 0, 0);          \
      }                                                                     \
    }                                                                       \
    __builtin_amdgcn_s_setprio(0);                                          \
  } while (0)

template <int MODE>
__global__ __launch_bounds__(512, 2) void gemm256(
    const bf16* __restrict__ A, const bf16* __restrict__ B,
    float* __restrict__ outf, bf16* __restrict__ outb,
    const bf16* __restrict__ o_in, const float* __restrict__ rmssum,
    const float* __restrict__ gnw, int N, int K, int ostr) {
  __shared__ bf16 lA[2][16384];  // [buf][half*8192 + row*64 + col]
  __shared__ bf16 lB[2][16384];
  const int tid = threadIdx.x;
  const int lane = tid & 63;
  const int wave = tid >> 6;
  const int wmi = wave >> 2;   // 0..1  (M wave index)
  const int wni = wave & 3;    // 0..3  (N wave index)
  const int l15 = lane & 15, l4 = lane >> 4;
  const int axor = l15 & 7;

  // T1: bijective XCD swizzle (grid = 256 blocks, % 8 == 0)
  const int nwg = gridDim.x;
  const int cpx = nwg >> 3;
  int wg = blockIdx.x;
  wg = (wg & 7) * cpx + (wg >> 3);
  const int NBN = N >> 8;
  const int bm = (wg / NBN) * 256;
  const int bn = (wg % NBN) * 256;

  // staging: chunk c = tid -> (row = tid>>3, slot = tid&7); global source
  // pre-swizzled (slot ^ row&7) so linear LDS dest + XOR read = identity.
  const int srow = tid >> 3;
  const int scol = ((tid & 7) ^ (srow & 7)) * 8;
  const size_t goff = (size_t)srow * K + scol;
  const int NT = K >> 6;

  const bf16* Ab = A + (size_t)bm * K + goff;
  const bf16* Bb = B + (size_t)bn * K + goff;

  auto stageA = [&](int kt, int h, int buf) {
    const int t = (kt < NT) ? kt : (NT - 1);  // tail: dummy re-stage
    const bf16* g = Ab + (size_t)h * 128 * K + t * 64;
    bf16* d = &lA[buf][h * 8192] + tid * 8;
    async16(d, g);
    async16(d + 4096, g + (size_t)64 * K);
  };
  auto stageB = [&](int kt, int h, int buf) {
    const int t = (kt < NT) ? kt : (NT - 1);
    const bf16* g = Bb + (size_t)h * 128 * K + t * 64;
    bf16* d = &lB[buf][h * 8192] + tid * 8;
    async16(d, g);
    async16(d + 4096, g + (size_t)64 * K);
  };

  auto readA = [&](bf16x8 (&af)[4][2], int buf, int mh) {
    const bf16* base = &lA[buf][wmi * 8192];
#pragma unroll
    for (int mt = 0; mt < 4; ++mt)
#pragma unroll
      for (int ks = 0; ks < 2; ++ks)
        af[mt][ks] = *(const bf16x8*)(base + (mh * 64 + mt * 16 + l15) * 64 +
                                      (((ks * 4 + l4) ^ axor) << 3));
  };
  auto readB = [&](bf16x8 (&bb)[2][2], int buf, int nh) {
    const bf16* base = &lB[buf][(wni >> 1) * 8192];
#pragma unroll
    for (int nt = 0; nt < 2; ++nt)
#pragma unroll
      for (int ks = 0; ks < 2; ++ks)
        bb[nt][ks] = *(const bf16x8*)(base +
                                      ((wni & 1) * 64 + nh * 32 + nt * 16 + l15) * 64 +
                                      (((ks * 4 + l4) ^ axor) << 3));
  };

  const f32x4 fz = {0.f, 0.f, 0.f, 0.f};
  f32x4 acc[8][4];
#pragma unroll
  for (int i = 0; i < 8; ++i)
#pragma unroll
    for (int j = 0; j < 4; ++j) acc[i][j] = fz;

  // ---- prologue: tile0 (B,A) + tile1 B. vmcnt(4) -> tile0 resident.
  stageB(0, 0, 0); stageB(0, 1, 0);
  stageA(0, 0, 0); stageA(0, 1, 0);
  stageB(1, 0, 1); stageB(1, 1, 1);
  asm volatile("s_waitcnt vmcnt(4)" ::: "memory");
  __builtin_amdgcn_s_barrier();
  __builtin_amdgcn_sched_barrier(0);  // no LDS reads above this point

  bf16x8 aF[4][2], b0F[2][2], b1F[2][2];

  auto ktile = [&](int kt, int cur, int nxt) {
    // -- phase 1: quadrant (0,0); stage (kt+1).A-h0 -> idle buf
    readA(aF, cur, 0);
    readB(b0F, cur, 0);
    stageA(kt + 1, 0, nxt);
    asm volatile("s_waitcnt lgkmcnt(8)" ::: "memory");
    __builtin_amdgcn_s_barrier();
    asm volatile("s_waitcnt lgkmcnt(0)" ::: "memory");
    QMFMA(aF, b0F, 0, 0);
    __builtin_amdgcn_s_barrier();
    // -- phase 2: quadrant (0,1); stage (kt+1).A-h1
    readB(b1F, cur, 1);
    stageA(kt + 1, 1, nxt);
    __builtin_amdgcn_s_barrier();
    asm volatile("s_waitcnt lgkmcnt(0)" ::: "memory");
    QMFMA(aF, b1F, 0, 1);
    __builtin_amdgcn_s_barrier();
    // -- phase 3: quadrant (1,0); stage (kt+2).B-h0 into cur (B fully read)
    readA(aF, cur, 1);
    stageB(kt + 2, 0, cur);
    __builtin_amdgcn_s_barrier();
    asm volatile("s_waitcnt lgkmcnt(0)" ::: "memory");
    QMFMA(aF, b0F, 1, 0);
    __builtin_amdgcn_s_barrier();
    // -- phase 4: quadrant (1,1); stage (kt+2).B-h1; counted vmcnt(4)
    //    drains (kt+1) A+B, leaves (kt+2).B halves in flight.
    stageB(kt + 2, 1, cur);
    asm volatile("s_waitcnt vmcnt(4)" ::: "memory");
    __builtin_amdgcn_s_barrier();
    __builtin_amdgcn_sched_barrier(0);  // next-tile ds_reads stay below here
    QMFMA(aF, b1F, 1, 1);
    __builtin_amdgcn_s_barrier();
  };

  for (int kt = 0; kt < NT; kt += 2) {  // NT even (32 or 64)
    ktile(kt, 0, 1);
    ktile(kt + 1, 1, 0);
  }

  // ---- epilogue
#pragma unroll
  for (int i = 0; i < 8; ++i) {
#pragma unroll
    for (int r = 0; r < 4; ++r) {
      const int gr = bm + wmi * 128 + i * 16 + l4 * 4 + r;
      float rinv = 0.f;
      if (MODE == 1) rinv = rsqrtf(rmssum[gr] * (1.f / 2048.f) + 1e-5f);
#pragma unroll
      for (int j = 0; j < 4; ++j) {
        const int gc = bn + wni * 64 + j * 16 + l15;
        const float v = acc[i][j][r];
        if (MODE == 1) {
          const float o = (float)o_in[(size_t)gr * ostr + gc];
          const float on = o * rinv * gnw[gc];
          const float sw = v / (1.f + __expf(-v));   // go*sigmoid(go)
          outb[(size_t)gr * N + gc] = __float2bfloat16(on * sw);
        } else {
          outf[(size_t)gr * N + gc] = v;
        }
      }
    }
  }
}

// ---------------------------------------------------------------------------
// per-row: q = softmax(logits[0:128]), k = sigmoid(logits[128:256]),
// gf = log_sigmoid(-k) = -log(1+exp(k)).  One wave per row. Also zeroes
// the per-row RMS partial-sum accumulator consumed later.
// ---------------------------------------------------------------------------
__global__ __launch_bounds__(64) void qk_post_kernel(
    const float* __restrict__ logits, bf16* __restrict__ qb,
    bf16* __restrict__ kb, float* __restrict__ gfl, float* __restrict__ rmssum) {
  const int row = blockIdx.x;
  const int t = threadIdx.x;
  if (t == 0) rmssum[row] = 0.f;
  const float* lr = logits + (size_t)row * 256;
  float a0 = lr[t], a1 = lr[t + 64];
  float m = fmaxf(a0, a1);
#pragma unroll
  for (int s = 32; s; s >>= 1) m = fmaxf(m, __shfl_xor(m, s));
  float e0 = __expf(a0 - m), e1 = __expf(a1 - m);
  float sum = e0 + e1;
#pragma unroll
  for (int s = 32; s; s >>= 1) sum += __shfl_xor(sum, s);
  const float inv = 1.f / sum;
  qb[(size_t)row * 128 + t]      = __float2bfloat16(e0 * inv);
  qb[(size_t)row * 128 + t + 64] = __float2bfloat16(e1 * inv);
  float b0 = lr[128 + t], b1 = lr[128 + t + 64];
  float k0 = 1.f / (1.f + __expf(-b0));
  float k1 = 1.f / (1.f + __expf(-b1));
  kb[(size_t)row * 128 + t]      = __float2bfloat16(k0);
  kb[(size_t)row * 128 + t + 64] = __float2bfloat16(k1);
  gfl[(size_t)row * 128 + t]      = -log1pf(__expf(k0));
  gfl[(size_t)row * 128 + t + 64] = -log1pf(__expf(k1));
}

// ---------------------------------------------------------------------------
// GLA sliding-window kernel. Block = (chunk, batch, dv-half); 64 out rows,
// 1024 of 2048 dv columns. Factor/score phases duplicated across the two
// dv-halves (cheap); V-MFMA and output split. RMS: raw partial sums via
// atomicAdd (rsqrt applied in gemm256<1> epilogue). ob stride 4096 (Acomb).
// ---------------------------------------------------------------------------
__global__ __launch_bounds__(256, 2) void gla_kernel(
    const bf16* __restrict__ qb, const bf16* __restrict__ kb,
    const float* __restrict__ gfl, const bf16* __restrict__ xbT,
    bf16* __restrict__ ob, float* __restrict__ rmssum) {
  __shared__ bf16 sF1[64][136];   // q*e^{Bi-M}; later reused as masked A[i][jw]
  __shared__ bf16 sF2[128][136];  // rows 0..63 prev-chunk, 64..127 current
  __shared__ float sM[128];
  __shared__ float rowsq[64];
  const int tid = threadIdx.x;
  const int lane = tid & 63, wave = tid >> 6;
  const int l15 = lane & 15, l4 = lane >> 4;
  const int chunk = blockIdx.x, b = blockIdx.y, z = blockIdx.z;
  const int row0 = b * 4096 + chunk * 64;

  if (tid < 64) rowsq[tid] = 0.f;

  if (tid < 128) {
    float s = 0.f;
    for (int i = 0; i <= 32; ++i) s += gfl[(size_t)(row0 + i) * 128 + tid];
    sM[tid] = s;
  }
  __syncthreads();

  if (tid < 128) {
    const int d = tid;
    const float M = sM[d];
    float bi = 0.f;
    for (int i = 0; i < 64; ++i) {
      bi += gfl[(size_t)(row0 + i) * 128 + d];
      const float q = (float)qb[(size_t)(row0 + i) * 128 + d];
      const float k = (float)kb[(size_t)(row0 + i) * 128 + d];
      sF1[i][d]      = __float2bfloat16(q * __expf(bi - M));
      sF2[64 + i][d] = __float2bfloat16(k * __expf(M - bi));
    }
  } else {
    const int d = tid - 128;
    if (chunk == 0) {
      for (int j = 0; j < 64; ++j) sF2[j][d] = __float2bfloat16(0.f);
    } else {
      const float M = sM[d];
      float bw = 0.f;
      for (int j = 63; j >= 0; --j) {
        const float k = (float)kb[(size_t)(row0 - 64 + j) * 128 + d];
        sF2[j][d] = __float2bfloat16(k * __expf(M - bw));
        bw -= gfl[(size_t)(row0 - 64 + j) * 128 + d];
      }
    }
  }
  __syncthreads();

  const f32x4 fz = {0.f, 0.f, 0.f, 0.f};
  {
    f32x4 sacc[4][2];
#pragma unroll
    for (int mt = 0; mt < 4; ++mt) { sacc[mt][0] = fz; sacc[mt][1] = fz; }
    bf16x8 f1[4][4];
#pragma unroll
    for (int kt = 0; kt < 4; ++kt)
#pragma unroll
      for (int mt = 0; mt < 4; ++mt)
        f1[kt][mt] = *(const bf16x8*)(&sF1[mt * 16 + l15][kt * 32 + l4 * 8]);
#pragma unroll
    for (int nt = 0; nt < 2; ++nt)
#pragma unroll
      for (int kt = 0; kt < 4; ++kt) {
        const bf16x8 f2 = *(const bf16x8*)(&sF2[wave * 32 + nt * 16 + l15][kt * 32 + l4 * 8]);
#pragma unroll
        for (int mt = 0; mt < 4; ++mt)
          sacc[mt][nt] = __builtin_amdgcn_mfma_f32_16x16x32_bf16(f1[kt][mt], f2, sacc[mt][nt], 0, 0, 0);
      }
    __syncthreads();
#pragma unroll
    for (int mt = 0; mt < 4; ++mt)
#pragma unroll
      for (int nt = 0; nt < 2; ++nt)
#pragma unroll
        for (int r = 0; r < 4; ++r) {
          const int i = mt * 16 + l4 * 4 + r;
          const int jw = wave * 32 + nt * 16 + l15;
          const bool ok = (jw < 64) || (jw - 64 <= i);
          sF1[i][jw] = __float2bfloat16(ok ? sacc[mt][nt][r] : 0.f);
        }
    __syncthreads();
  }

  bf16x8 av[4][4];
#pragma unroll
  for (int kt = 0; kt < 4; ++kt)
#pragma unroll
    for (int mt = 0; mt < 4; ++mt)
      av[kt][mt] = *(const bf16x8*)(&sF1[mt * 16 + l15][kt * 32 + l4 * 8]);

  float rs[4][4];
#pragma unroll
  for (int a = 0; a < 4; ++a)
#pragma unroll
    for (int r2 = 0; r2 < 4; ++r2) rs[a][r2] = 0.f;

  const int lwb = chunk * 64 - 64;
  for (int dt = z * 4; dt < z * 4 + 4; ++dt) {
    const int c0 = dt * 256 + wave * 64;
    f32x4 oacc[4][4];
#pragma unroll
    for (int mt = 0; mt < 4; ++mt)
#pragma unroll
      for (int nt = 0; nt < 4; ++nt) oacc[mt][nt] = fz;
#pragma unroll
    for (int kt = 0; kt < 4; ++kt)
#pragma unroll
      for (int nt = 0; nt < 4; ++nt) {
        const int dv = c0 + nt * 16 + l15;
        int lw = lwb + kt * 32 + l4 * 8;
        if (lw < 0) lw = 0;  // chunk 0 prev-half: A==0, any valid addr is fine
        const bf16x8 vv = *(const bf16x8*)(xbT + ((size_t)b * 2048 + dv) * 4096 + lw);
#pragma unroll
        for (int mt = 0; mt < 4; ++mt)
          oacc[mt][nt] = __builtin_amdgcn_mfma_f32_16x16x32_bf16(av[kt][mt], vv, oacc[mt][nt], 0, 0, 0);
      }
#pragma unroll
    for (int mt = 0; mt < 4; ++mt)
#pragma unroll
      for (int r = 0; r < 4; ++r) {
        const int i = mt * 16 + l4 * 4 + r;
#pragma unroll
        for (int nt = 0; nt < 4; ++nt) {
          const float v = oacc[mt][nt][r];
          ob[(size_t)(row0 + i) * 4096 + (c0 + nt * 16 + l15)] = __float2bfloat16(v);
          rs[mt][r] += v * v;
        }
      }
  }

#pragma unroll
  for (int mt = 0; mt < 4; ++mt)
#pragma unroll
    for (int r = 0; r < 4; ++r) {
      float v = rs[mt][r];
      v += __shfl_xor(v, 1); v += __shfl_xor(v, 2);
      v += __shfl_xor(v, 4); v += __shfl_xor(v, 8);
      if (l15 == 0) atomicAdd(&rowsq[mt * 16 + l4 * 4 + r], v);
    }
  __syncthreads();
  if (tid < 64)
    atomicAdd(&rmssum[row0 + tid], rowsq[tid]);
}

// ---------------------------------------------------------------------------
extern "C" void kernel_launch(void* const* d_in, const int* in_sizes, int n_in,
                              void* d_out, int out_size, void* d_ws, size_t ws_size,
                              hipStream_t stream) {
  const float* x   = (const float*)d_in[0];
  const float* Wq  = (const float*)d_in[1];
  const float* Wk  = (const float*)d_in[2];
  const float* Wog = (const float*)d_in[3];
  const float* Wig = (const float*)d_in[4];
  const float* Wo  = (const float*)d_in[5];
  const float* gnw = (const float*)d_in[6];
  float* out = (float*)d_out;

  char* w = (char*)d_ws;
  auto alloc = [&](size_t bytes) {
    char* p = w;
    w += (bytes + 255) & ~(size_t)255;
    return p;
  };
  bf16*  wqkb   = (bf16*)alloc((size_t)256 * 2048 * 2);
  bf16*  wcomb  = (bf16*)alloc((size_t)2048 * 4096 * 2);   // [Wog | Wig]
  bf16*  wob    = (bf16*)alloc((size_t)2048 * 2048 * 2);
  bf16*  acomb  = (bf16*)alloc((size_t)8192 * 4096 * 2);   // [o | x] per row
  bf16*  xbT    = (bf16*)alloc((size_t)8192 * 2048 * 2);
  float* logits = (float*)alloc((size_t)8192 * 256 * 4);
  bf16*  qbuf   = (bf16*)alloc((size_t)8192 * 128 * 2);
  bf16*  kbuf   = (bf16*)alloc((size_t)8192 * 128 * 2);
  float* gfbuf  = (float*)alloc((size_t)8192 * 128 * 4);
  float* rmsbuf = (float*)alloc((size_t)8192 * 4);
  bf16*  gatedb = xbT;  // xbT dead after gla_kernel -> reuse for gated

  // weights -> bf16
  cvt_bf16_kernel<<<dim3((65536 + 255) / 256), 256, 0, stream>>>(Wq, wqkb, 65536);
  cvt_bf16_kernel<<<dim3((65536 + 255) / 256), 256, 0, stream>>>(Wk, wqkb + 262144, 65536);
  cvt_bf16_strided<<<dim3((1048576 + 255) / 256), 256, 0, stream>>>(Wog, wcomb, 1048576);
  cvt_bf16_strided<<<dim3((1048576 + 255) / 256), 256, 0, stream>>>(Wig, wcomb + 2048, 1048576);
  cvt_bf16_kernel<<<dim3((1048576 + 255) / 256), 256, 0, stream>>>(Wo, wob, 1048576);

  // x -> acomb[:, 2048:4096] + xbT
  convert_x_kernel<<<dim3(64, 32, 2), 256, 0, stream>>>(x, acomb, xbT);

  // logits = x @ [Wq;Wk]^T   (A = x-half of acomb, lda 4096)
  gemm_logits<<<dim3(64, 2), 256, 0, stream>>>(
      acomb + 2048, wqkb, logits, 4096, 256, 2048);

  // q/k/gf (+ rms accumulator zero)
  qk_post_kernel<<<dim3(8192), 64, 0, stream>>>(logits, qbuf, kbuf, gfbuf, rmsbuf);

  // GLA -> o (bf16, into acomb[:, 0:2048]) + rms partial sums
  gla_kernel<<<dim3(64, 2, 2), 256, 0, stream>>>(qbuf, kbuf, gfbuf, xbT, acomb, rmsbuf);

  // go = [o|x] @ [Wog|Wig]^T (K=4096); gated = RMSNorm(o)*g * swish(go)
  gemm256<1><<<dim3(256), 512, 0, stream>>>(
      acomb, wcomb, nullptr, gatedb, acomb, rmsbuf, gnw, 2048, 4096, 4096);

  // out = gated @ Wo^T
  gemm256<2><<<dim3(256), 512, 0, stream>>>(
      gatedb, wob, out, nullptr, nullptr, nullptr, nullptr, 2048, 2048, 2048);

  (void)in_sizes; (void)n_in; (void)out_size; (void)ws_size;
}

// Round 4
// 444.931 us; speedup vs baseline: 1.0638x; 1.0638x over previous
//
#include <hip/hip_runtime.h>
#include <hip/hip_bf16.h>

typedef __hip_bfloat16 bf16;
typedef __bf16 bf16x8 __attribute__((ext_vector_type(8)));
typedef float f32x4 __attribute__((ext_vector_type(4)));

// async global->LDS, 16B per lane. LDS dest = wave-uniform base + lane*16.
__device__ __forceinline__ void async16(void* lds_base, const void* g) {
  __builtin_amdgcn_global_load_lds(
      (const __attribute__((address_space(1))) void*)g,
      (__attribute__((address_space(3))) void*)lds_base, 16, 0, 0);
}

// ---------------------------------------------------------------------------
// f32 -> bf16 flat convert (weights)
// ---------------------------------------------------------------------------
__global__ void cvt_bf16_kernel(const float* __restrict__ s, bf16* __restrict__ d, int n4) {
  const int i = blockIdx.x * 256 + threadIdx.x;
  if (i >= n4) return;
  const float4 v = ((const float4*)s)[i];
  bf16 h0 = __float2bfloat16(v.x), h1 = __float2bfloat16(v.y);
  bf16 h2 = __float2bfloat16(v.z), h3 = __float2bfloat16(v.w);
  ushort4 o;
  o.x = *(unsigned short*)&h0; o.y = *(unsigned short*)&h1;
  o.z = *(unsigned short*)&h2; o.w = *(unsigned short*)&h3;
  *(ushort4*)((unsigned short*)d + (size_t)i * 4) = o;
}

// f32 [2048][2048] -> bf16 into rows of stride 4096 (for [Wog|Wig] K-merge)
__global__ void cvt_bf16_strided(const float* __restrict__ s, bf16* __restrict__ d, int n4) {
  const int i = blockIdx.x * 256 + threadIdx.x;
  if (i >= n4) return;
  const int row = i >> 9;          // 512 float4 per 2048-col row
  const int col4 = i & 511;
  const float4 v = ((const float4*)s)[i];
  bf16 h0 = __float2bfloat16(v.x), h1 = __float2bfloat16(v.y);
  bf16 h2 = __float2bfloat16(v.z), h3 = __float2bfloat16(v.w);
  ushort4 o;
  o.x = *(unsigned short*)&h0; o.y = *(unsigned short*)&h1;
  o.z = *(unsigned short*)&h2; o.w = *(unsigned short*)&h3;
  *(ushort4*)((unsigned short*)d + (size_t)row * 4096 + col4 * 4) = o;
}

// ---------------------------------------------------------------------------
// x (B,L,H) fp32 -> comb[.., 2048..4095] bf16 (A-matrix K-merge half)
//                 + xbT (B,H,L) bf16 (for GLA V-frags). Vectorized 16B/8B.
// ---------------------------------------------------------------------------
__global__ __launch_bounds__(256) void convert_x_kernel(
    const float* __restrict__ x, bf16* __restrict__ comb, bf16* __restrict__ xbT) {
  __shared__ float tile[64][65];
  const int b = blockIdx.z;
  const int l0 = blockIdx.x * 64, d0 = blockIdx.y * 64;
  const int t = threadIdx.x;
  const int c4 = (t & 15) * 4, r = t >> 4;  // r 0..15
  const size_t base = ((size_t)b * 4096 + l0) * 2048 + d0;
#pragma unroll
  for (int i = 0; i < 4; ++i) {
    const int row = i * 16 + r;
    const float4 v = *(const float4*)(x + base + (size_t)row * 2048 + c4);
    tile[row][c4 + 0] = v.x; tile[row][c4 + 1] = v.y;
    tile[row][c4 + 2] = v.z; tile[row][c4 + 3] = v.w;
    bf16 h0 = __float2bfloat16(v.x), h1 = __float2bfloat16(v.y);
    bf16 h2 = __float2bfloat16(v.z), h3 = __float2bfloat16(v.w);
    ushort4 o;
    o.x = *(unsigned short*)&h0; o.y = *(unsigned short*)&h1;
    o.z = *(unsigned short*)&h2; o.w = *(unsigned short*)&h3;
    *(ushort4*)(comb + ((size_t)(b * 4096 + l0 + row)) * 4096 + 2048 + d0 + c4) = o;
  }
  __syncthreads();
#pragma unroll
  for (int i = 0; i < 4; ++i) {
    const int d = i * 16 + r;
    bf16 h0 = __float2bfloat16(tile[c4 + 0][d]);
    bf16 h1 = __float2bfloat16(tile[c4 + 1][d]);
    bf16 h2 = __float2bfloat16(tile[c4 + 2][d]);
    bf16 h3 = __float2bfloat16(tile[c4 + 3][d]);
    ushort4 o;
    o.x = *(unsigned short*)&h0; o.y = *(unsigned short*)&h1;
    o.z = *(unsigned short*)&h2; o.w = *(unsigned short*)&h3;
    *(ushort4*)(xbT + ((size_t)(b * 2048 + d0 + d)) * 4096 + l0 + c4) = o;
  }
}

// ---------------------------------------------------------------------------
// m97-style bf16 GEMM for the small logits GEMM (N=256). lda-strided A.
// ---------------------------------------------------------------------------
__global__ __launch_bounds__(256, 2) void gemm_logits(
    const bf16* __restrict__ A, const bf16* __restrict__ B,
    float* __restrict__ outf, int lda, int N, int K) {
  __shared__ bf16 lA[128 * 32];
  __shared__ bf16 lB[128 * 32];
  const int tid = threadIdx.x;
  const int lane = tid & 63, wave = tid >> 6;
  const int l15 = lane & 15, l4 = lane >> 4;
  const int bm = blockIdx.x * 128, bn = blockIdx.y * 128;
  const int wm = (wave & 1) * 64, wn = (wave >> 1) * 64;
  const int srow = tid >> 2;
  const int skc = (tid & 3) * 8;

  const f32x4 fz = {0.f, 0.f, 0.f, 0.f};
  f32x4 acc[4][4];
#pragma unroll
  for (int i = 0; i < 4; ++i)
#pragma unroll
    for (int j = 0; j < 4; ++j) acc[i][j] = fz;

  bf16* lAu  = lA + wave * 512;
  bf16* lAu2 = lA + 2048 + wave * 512;
  bf16* lBu  = lB + wave * 512;
  bf16* lBu2 = lB + 2048 + wave * 512;

  const bf16* gA0 = A + (size_t)(bm + srow) * lda + skc;
  const bf16* gA1 = A + (size_t)(bm + srow + 64) * lda + skc;
  const bf16* gB0 = B + (size_t)(bn + srow) * K + skc;
  const bf16* gB1 = B + (size_t)(bn + srow + 64) * K + skc;
  for (int k0 = 0; k0 < K; k0 += 32) {
    __syncthreads();
    async16(lAu, gA0 + k0);
    async16(lAu2, gA1 + k0);
    async16(lBu, gB0 + k0);
    async16(lBu2, gB1 + k0);
    __syncthreads();
    bf16x8 af[4], bfv[4];
#pragma unroll
    for (int mt = 0; mt < 4; ++mt)
      af[mt] = *(const bf16x8*)(lA + (wm + mt * 16 + l15) * 32 + l4 * 8);
#pragma unroll
    for (int nt = 0; nt < 4; ++nt)
      bfv[nt] = *(const bf16x8*)(lB + (wn + nt * 16 + l15) * 32 + l4 * 8);
#pragma unroll
    for (int mt = 0; mt < 4; ++mt)
#pragma unroll
      for (int nt = 0; nt < 4; ++nt)
        acc[mt][nt] = __builtin_amdgcn_mfma_f32_16x16x32_bf16(af[mt], bfv[nt], acc[mt][nt], 0, 0, 0);
  }

#pragma unroll
  for (int mt = 0; mt < 4; ++mt)
#pragma unroll
    for (int r = 0; r < 4; ++r) {
      const int gr = bm + wm + mt * 16 + l4 * 4 + r;
#pragma unroll
      for (int nt = 0; nt < 4; ++nt) {
        const int gc = bn + wn + nt * 16 + l15;
        outf[(size_t)gr * N + gc] = acc[mt][nt][r];
      }
    }
}

// ---------------------------------------------------------------------------
// 256x256-tile 8-phase bf16 GEMM with FRAGMENT READ-AHEAD:
// each phase issues ds_reads for the NEXT phase's fragments, then waits
// lgkmcnt(N_just_issued) so only the PREVIOUS phase's reads are drained ->
// LDS service overlaps the MFMA cluster. Counted vmcnt (8,8,10,10) at phase
// ends, each draining one half-tile staged 4-5 phases earlier.
// T1 XCD-swizzle + T2 LDS XOR-swizzle + T5 setprio. K = 64*NT (2048/4096).
// MODE 1: RMSNorm-gate-swish epilogue -> bf16.  MODE 2: fp32 out.
// 512 threads = 8 waves (2M x 4N); per-wave out 128x64; BK=64; LDS 128 KiB.
// ---------------------------------------------------------------------------
#define QMFMA(AF, BF, MH, NH)                                               \
  do {                                                                      \
    __builtin_amdgcn_s_setprio(1);                                          \
    _Pragma("unroll") for (int ks_ = 0; ks_ < 2; ++ks_) {                   \
      _Pragma("unroll") for (int mt_ = 0; mt_ < 4; ++mt_) {                 \
        _Pragma("unroll") for (int nt_ = 0; nt_ < 2; ++nt_)                 \
            acc[(MH) * 4 + mt_][(NH) * 2 + nt_] =                           \
                __builtin_amdgcn_mfma_f32_16x16x32_bf16(                    \
                    AF[mt_][ks_], BF[nt_][ks_],                             \
                    acc[(MH) * 4 + mt_][(NH) * 2 + nt_], 0, 0, 0);          \
      }                                                                     \
    }                                                                       \
    __builtin_amdgcn_s_setprio(0);                                          \
  } while (0)

template <int MODE>
__global__ __launch_bounds__(512, 2) void gemm256(
    const bf16* __restrict__ A, const bf16* __restrict__ B,
    float* __restrict__ outf, bf16* __restrict__ outb,
    const bf16* __restrict__ o_in, const float* __restrict__ rmssum,
    const float* __restrict__ gnw, int N, int K, int ostr) {
  __shared__ bf16 lA[2][16384];  // [buf][half*8192 + row*64 + col]
  __shared__ bf16 lB[2][16384];
  const int tid = threadIdx.x;
  const int lane = tid & 63;
  const int wave = tid >> 6;
  const int wmi = wave >> 2;   // 0..1  (M wave index)
  const int wni = wave & 3;    // 0..3  (N wave index)
  const int l15 = lane & 15, l4 = lane >> 4;
  const int axor = l15 & 7;

  // T1: bijective XCD swizzle (grid = 256 blocks, % 8 == 0)
  const int nwg = gridDim.x;
  const int cpx = nwg >> 3;
  int wg = blockIdx.x;
  wg = (wg & 7) * cpx + (wg >> 3);
  const int NBN = N >> 8;
  const int bm = (wg / NBN) * 256;
  const int bn = (wg % NBN) * 256;

  // staging: chunk c = tid -> (row = tid>>3, slot = tid&7); global source
  // pre-swizzled (slot ^ row&7) so linear LDS dest + XOR read = identity.
  const int srow = tid >> 3;
  const int scol = ((tid & 7) ^ (srow & 7)) * 8;
  const size_t goff = (size_t)srow * K + scol;
  const int NT = K >> 6;

  const bf16* Ab = A + (size_t)bm * K + goff;
  const bf16* Bb = B + (size_t)bn * K + goff;

  auto stageA = [&](int kt, int h, int buf) {
    const int t = (kt < NT) ? kt : (NT - 1);  // tail: dummy re-stage
    const bf16* g = Ab + (size_t)h * 128 * K + t * 64;
    bf16* d = &lA[buf][h * 8192] + tid * 8;
    async16(d, g);
    async16(d + 4096, g + (size_t)64 * K);
  };
  auto stageB = [&](int kt, int h, int buf) {
    const int t = (kt < NT) ? kt : (NT - 1);
    const bf16* g = Bb + (size_t)h * 128 * K + t * 64;
    bf16* d = &lB[buf][h * 8192] + tid * 8;
    async16(d, g);
    async16(d + 4096, g + (size_t)64 * K);
  };

  auto readA = [&](bf16x8 (&af)[4][2], int buf, int mh) {
    const bf16* base = &lA[buf][wmi * 8192];
#pragma unroll
    for (int mt = 0; mt < 4; ++mt)
#pragma unroll
      for (int ks = 0; ks < 2; ++ks)
        af[mt][ks] = *(const bf16x8*)(base + (mh * 64 + mt * 16 + l15) * 64 +
                                      (((ks * 4 + l4) ^ axor) << 3));
  };
  auto readB = [&](bf16x8 (&bb)[2][2], int buf, int nh) {
    const bf16* base = &lB[buf][(wni >> 1) * 8192];
#pragma unroll
    for (int nt = 0; nt < 2; ++nt)
#pragma unroll
      for (int ks = 0; ks < 2; ++ks)
        bb[nt][ks] = *(const bf16x8*)(base +
                                      ((wni & 1) * 64 + nh * 32 + nt * 16 + l15) * 64 +
                                      (((ks * 4 + l4) ^ axor) << 3));
  };

  const f32x4 fz = {0.f, 0.f, 0.f, 0.f};
  f32x4 acc[8][4];
#pragma unroll
  for (int i = 0; i < 8; ++i)
#pragma unroll
    for (int j = 0; j < 4; ++j) acc[i][j] = fz;

  // fragment sets (loop-carried; read one phase ahead of use)
  bf16x8 aH0[4][2], aH1[4][2], b0[2][2], b1[2][2];

  // ---- prologue: stage tile0 fully + tile1 (A1h0, B1h0, B1h1, A1h1).
  stageA(0, 0, 0); stageA(0, 1, 0); stageB(0, 0, 0); stageB(0, 1, 0);
  stageA(1, 0, 1); stageB(1, 0, 1); stageB(1, 1, 1); stageA(1, 1, 1);
  asm volatile("s_waitcnt vmcnt(8)" ::: "memory");   // tile0 resident
  __builtin_amdgcn_s_barrier();
  // pre-read ph1(0) fragments (completed under ph1's lgkmcnt(4))
  readA(aH0, 0, 0);
  readB(b0, 0, 0);
  __builtin_amdgcn_sched_barrier(0);

  auto ktile = [&](int kt, int cur, int nxt) {
    // -- ph1: MFMA Q(0,0)=aH0*b0 ; read b1 <- B(kt)h1 (cur)
    readB(b1, cur, 1);
    __builtin_amdgcn_sched_barrier(0);
    __builtin_amdgcn_s_barrier();
    asm volatile("s_waitcnt lgkmcnt(4)" ::: "memory");
    __builtin_amdgcn_sched_barrier(0);
    QMFMA(aH0, b0, 0, 0);
    asm volatile("s_waitcnt vmcnt(8)" ::: "memory");
    __builtin_amdgcn_s_barrier();
    // -- ph2: MFMA Q(0,1)=aH0*b1 ; read aH1 <- A(kt)h1 (cur); stage A(kt+2)h0
    readA(aH1, cur, 1);
    stageA(kt + 2, 0, cur);
    __builtin_amdgcn_sched_barrier(0);
    __builtin_amdgcn_s_barrier();
    asm volatile("s_waitcnt lgkmcnt(8)" ::: "memory");
    __builtin_amdgcn_sched_barrier(0);
    QMFMA(aH0, b1, 0, 1);
    asm volatile("s_waitcnt vmcnt(8)" ::: "memory");
    __builtin_amdgcn_s_barrier();
    // -- ph3: MFMA Q(1,0)=aH1*b0 ; read aH0 <- A(kt+1)h0 (nxt); stage B(kt+2)
    readA(aH0, nxt, 0);
    stageB(kt + 2, 0, cur);
    stageB(kt + 2, 1, cur);
    __builtin_amdgcn_sched_barrier(0);
    __builtin_amdgcn_s_barrier();
    asm volatile("s_waitcnt lgkmcnt(8)" ::: "memory");
    __builtin_amdgcn_sched_barrier(0);
    QMFMA(aH1, b0, 1, 0);
    asm volatile("s_waitcnt vmcnt(10)" ::: "memory");
    __builtin_amdgcn_s_barrier();
    // -- ph4: MFMA Q(1,1)=aH1*b1 ; read b0 <- B(kt+1)h0 (nxt); stage A(kt+2)h1
    readB(b0, nxt, 0);
    stageA(kt + 2, 1, cur);
    __builtin_amdgcn_sched_barrier(0);
    __builtin_amdgcn_s_barrier();
    asm volatile("s_waitcnt lgkmcnt(12)" ::: "memory");
    __builtin_amdgcn_sched_barrier(0);
    QMFMA(aH1, b1, 1, 1);
    asm volatile("s_waitcnt vmcnt(10)" ::: "memory");
    __builtin_amdgcn_s_barrier();
  };

  for (int kt = 0; kt < NT; kt += 2) {  // NT even (32 or 64)
    ktile(kt, 0, 1);
    ktile(kt + 1, 1, 0);
  }
  asm volatile("s_waitcnt vmcnt(0) lgkmcnt(0)" ::: "memory");
  __builtin_amdgcn_s_barrier();

  // ---- epilogue
#pragma unroll
  for (int i = 0; i < 8; ++i) {
#pragma unroll
    for (int r = 0; r < 4; ++r) {
      const int gr = bm + wmi * 128 + i * 16 + l4 * 4 + r;
      float rinv = 0.f;
      if (MODE == 1) rinv = rsqrtf(rmssum[gr] * (1.f / 2048.f) + 1e-5f);
#pragma unroll
      for (int j = 0; j < 4; ++j) {
        const int gc = bn + wni * 64 + j * 16 + l15;
        const float v = acc[i][j][r];
        if (MODE == 1) {
          const float o = (float)o_in[(size_t)gr * ostr + gc];
          const float on = o * rinv * gnw[gc];
          const float sw = v / (1.f + __expf(-v));   // go*sigmoid(go)
          outb[(size_t)gr * N + gc] = __float2bfloat16(on * sw);
        } else {
          outf[(size_t)gr * N + gc] = v;
        }
      }
    }
  }
}

// ---------------------------------------------------------------------------
// per-row: q = softmax(logits[0:128]), k = sigmoid(logits[128:256]),
// gf = log_sigmoid(-k) = -log(1+exp(k)).  One wave per row. Also zeroes
// the per-row RMS partial-sum accumulator consumed later.
// ---------------------------------------------------------------------------
__global__ __launch_bounds__(64) void qk_post_kernel(
    const float* __restrict__ logits, bf16* __restrict__ qb,
    bf16* __restrict__ kb, float* __restrict__ gfl, float* __restrict__ rmssum) {
  const int row = blockIdx.x;
  const int t = threadIdx.x;
  if (t == 0) rmssum[row] = 0.f;
  const float* lr = logits + (size_t)row * 256;
  float a0 = lr[t], a1 = lr[t + 64];
  float m = fmaxf(a0, a1);
#pragma unroll
  for (int s = 32; s; s >>= 1) m = fmaxf(m, __shfl_xor(m, s));
  float e0 = __expf(a0 - m), e1 = __expf(a1 - m);
  float sum = e0 + e1;
#pragma unroll
  for (int s = 32; s; s >>= 1) sum += __shfl_xor(sum, s);
  const float inv = 1.f / sum;
  qb[(size_t)row * 128 + t]      = __float2bfloat16(e0 * inv);
  qb[(size_t)row * 128 + t + 64] = __float2bfloat16(e1 * inv);
  float b0 = lr[128 + t], b1 = lr[128 + t + 64];
  float k0 = 1.f / (1.f + __expf(-b0));
  float k1 = 1.f / (1.f + __expf(-b1));
  kb[(size_t)row * 128 + t]      = __float2bfloat16(k0);
  kb[(size_t)row * 128 + t + 64] = __float2bfloat16(k1);
  gfl[(size_t)row * 128 + t]      = -log1pf(__expf(k0));
  gfl[(size_t)row * 128 + t + 64] = -log1pf(__expf(k1));
}

// ---------------------------------------------------------------------------
// GLA sliding-window kernel. Block = (chunk, batch, dv-half); 64 out rows,
// 1024 of 2048 dv columns. ob stride 4096 (into acomb[:, 0:2048]).
// ---------------------------------------------------------------------------
__global__ __launch_bounds__(256, 2) void gla_kernel(
    const bf16* __restrict__ qb, const bf16* __restrict__ kb,
    const float* __restrict__ gfl, const bf16* __restrict__ xbT,
    bf16* __restrict__ ob, float* __restrict__ rmssum) {
  __shared__ bf16 sF1[64][136];   // q*e^{Bi-M}; later reused as masked A[i][jw]
  __shared__ bf16 sF2[128][136];  // rows 0..63 prev-chunk, 64..127 current
  __shared__ float sM[128];
  __shared__ float rowsq[64];
  const int tid = threadIdx.x;
  const int lane = tid & 63, wave = tid >> 6;
  const int l15 = lane & 15, l4 = lane >> 4;
  const int chunk = blockIdx.x, b = blockIdx.y, z = blockIdx.z;
  const int row0 = b * 4096 + chunk * 64;

  if (tid < 64) rowsq[tid] = 0.f;

  if (tid < 128) {
    float s = 0.f;
    for (int i = 0; i <= 32; ++i) s += gfl[(size_t)(row0 + i) * 128 + tid];
    sM[tid] = s;
  }
  __syncthreads();

  if (tid < 128) {
    const int d = tid;
    const float M = sM[d];
    float bi = 0.f;
    for (int i = 0; i < 64; ++i) {
      bi += gfl[(size_t)(row0 + i) * 128 + d];
      const float q = (float)qb[(size_t)(row0 + i) * 128 + d];
      const float k = (float)kb[(size_t)(row0 + i) * 128 + d];
      sF1[i][d]      = __float2bfloat16(q * __expf(bi - M));
      sF2[64 + i][d] = __float2bfloat16(k * __expf(M - bi));
    }
  } else {
    const int d = tid - 128;
    if (chunk == 0) {
      for (int j = 0; j < 64; ++j) sF2[j][d] = __float2bfloat16(0.f);
    } else {
      const float M = sM[d];
      float bw = 0.f;
      for (int j = 63; j >= 0; --j) {
        const float k = (float)kb[(size_t)(row0 - 64 + j) * 128 + d];
        sF2[j][d] = __float2bfloat16(k * __expf(M - bw));
        bw -= gfl[(size_t)(row0 - 64 + j) * 128 + d];
      }
    }
  }
  __syncthreads();

  const f32x4 fz = {0.f, 0.f, 0.f, 0.f};
  {
    f32x4 sacc[4][2];
#pragma unroll
    for (int mt = 0; mt < 4; ++mt) { sacc[mt][0] = fz; sacc[mt][1] = fz; }
    bf16x8 f1[4][4];
#pragma unroll
    for (int kt = 0; kt < 4; ++kt)
#pragma unroll
      for (int mt = 0; mt < 4; ++mt)
        f1[kt][mt] = *(const bf16x8*)(&sF1[mt * 16 + l15][kt * 32 + l4 * 8]);
#pragma unroll
    for (int nt = 0; nt < 2; ++nt)
#pragma unroll
      for (int kt = 0; kt < 4; ++kt) {
        const bf16x8 f2 = *(const bf16x8*)(&sF2[wave * 32 + nt * 16 + l15][kt * 32 + l4 * 8]);
#pragma unroll
        for (int mt = 0; mt < 4; ++mt)
          sacc[mt][nt] = __builtin_amdgcn_mfma_f32_16x16x32_bf16(f1[kt][mt], f2, sacc[mt][nt], 0, 0, 0);
      }
    __syncthreads();
#pragma unroll
    for (int mt = 0; mt < 4; ++mt)
#pragma unroll
      for (int nt = 0; nt < 2; ++nt)
#pragma unroll
        for (int r = 0; r < 4; ++r) {
          const int i = mt * 16 + l4 * 4 + r;
          const int jw = wave * 32 + nt * 16 + l15;
          const bool ok = (jw < 64) || (jw - 64 <= i);
          sF1[i][jw] = __float2bfloat16(ok ? sacc[mt][nt][r] : 0.f);
        }
    __syncthreads();
  }

  bf16x8 av[4][4];
#pragma unroll
  for (int kt = 0; kt < 4; ++kt)
#pragma unroll
    for (int mt = 0; mt < 4; ++mt)
      av[kt][mt] = *(const bf16x8*)(&sF1[mt * 16 + l15][kt * 32 + l4 * 8]);

  float rs[4][4];
#pragma unroll
  for (int a = 0; a < 4; ++a)
#pragma unroll
    for (int r2 = 0; r2 < 4; ++r2) rs[a][r2] = 0.f;

  const int lwb = chunk * 64 - 64;
  for (int dt = z * 4; dt < z * 4 + 4; ++dt) {
    const int c0 = dt * 256 + wave * 64;
    f32x4 oacc[4][4];
#pragma unroll
    for (int mt = 0; mt < 4; ++mt)
#pragma unroll
      for (int nt = 0; nt < 4; ++nt) oacc[mt][nt] = fz;
#pragma unroll
    for (int kt = 0; kt < 4; ++kt)
#pragma unroll
      for (int nt = 0; nt < 4; ++nt) {
        const int dv = c0 + nt * 16 + l15;
        int lw = lwb + kt * 32 + l4 * 8;
        if (lw < 0) lw = 0;  // chunk 0 prev-half: A==0, any valid addr is fine
        const bf16x8 vv = *(const bf16x8*)(xbT + ((size_t)b * 2048 + dv) * 4096 + lw);
#pragma unroll
        for (int mt = 0; mt < 4; ++mt)
          oacc[mt][nt] = __builtin_amdgcn_mfma_f32_16x16x32_bf16(av[kt][mt], vv, oacc[mt][nt], 0, 0, 0);
      }
#pragma unroll
    for (int mt = 0; mt < 4; ++mt)
#pragma unroll
      for (int r = 0; r < 4; ++r) {
        const int i = mt * 16 + l4 * 4 + r;
#pragma unroll
        for (int nt = 0; nt < 4; ++nt) {
          const float v = oacc[mt][nt][r];
          ob[(size_t)(row0 + i) * 4096 + (c0 + nt * 16 + l15)] = __float2bfloat16(v);
          rs[mt][r] += v * v;
        }
      }
  }

#pragma unroll
  for (int mt = 0; mt < 4; ++mt)
#pragma unroll
    for (int r = 0; r < 4; ++r) {
      float v = rs[mt][r];
      v += __shfl_xor(v, 1); v += __shfl_xor(v, 2);
      v += __shfl_xor(v, 4); v += __shfl_xor(v, 8);
      if (l15 == 0) atomicAdd(&rowsq[mt * 16 + l4 * 4 + r], v);
    }
  __syncthreads();
  if (tid < 64)
    atomicAdd(&rmssum[row0 + tid], rowsq[tid]);
}

// ---------------------------------------------------------------------------
extern "C" void kernel_launch(void* const* d_in, const int* in_sizes, int n_in,
                              void* d_out, int out_size, void* d_ws, size_t ws_size,
                              hipStream_t stream) {
  const float* x   = (const float*)d_in[0];
  const float* Wq  = (const float*)d_in[1];
  const float* Wk  = (const float*)d_in[2];
  const float* Wog = (const float*)d_in[3];
  const float* Wig = (const float*)d_in[4];
  const float* Wo  = (const float*)d_in[5];
  const float* gnw = (const float*)d_in[6];
  float* out = (float*)d_out;

  char* w = (char*)d_ws;
  auto alloc = [&](size_t bytes) {
    char* p = w;
    w += (bytes + 255) & ~(size_t)255;
    return p;
  };
  bf16*  wqkb   = (bf16*)alloc((size_t)256 * 2048 * 2);
  bf16*  wcomb  = (bf16*)alloc((size_t)2048 * 4096 * 2);   // [Wog | Wig]
  bf16*  wob    = (bf16*)alloc((size_t)2048 * 2048 * 2);
  bf16*  acomb  = (bf16*)alloc((size_t)8192 * 4096 * 2);   // [o | x] per row
  bf16*  xbT    = (bf16*)alloc((size_t)8192 * 2048 * 2);
  float* logits = (float*)alloc((size_t)8192 * 256 * 4);
  bf16*  qbuf   = (bf16*)alloc((size_t)8192 * 128 * 2);
  bf16*  kbuf   = (bf16*)alloc((size_t)8192 * 128 * 2);
  float* gfbuf  = (float*)alloc((size_t)8192 * 128 * 4);
  float* rmsbuf = (float*)alloc((size_t)8192 * 4);
  bf16*  gatedb = xbT;  // xbT dead after gla_kernel -> reuse for gated

  // weights -> bf16
  cvt_bf16_kernel<<<dim3((65536 + 255) / 256), 256, 0, stream>>>(Wq, wqkb, 65536);
  cvt_bf16_kernel<<<dim3((65536 + 255) / 256), 256, 0, stream>>>(Wk, wqkb + 262144, 65536);
  cvt_bf16_strided<<<dim3((1048576 + 255) / 256), 256, 0, stream>>>(Wog, wcomb, 1048576);
  cvt_bf16_strided<<<dim3((1048576 + 255) / 256), 256, 0, stream>>>(Wig, wcomb + 2048, 1048576);
  cvt_bf16_kernel<<<dim3((1048576 + 255) / 256), 256, 0, stream>>>(Wo, wob, 1048576);

  // x -> acomb[:, 2048:4096] + xbT
  convert_x_kernel<<<dim3(64, 32, 2), 256, 0, stream>>>(x, acomb, xbT);

  // logits = x @ [Wq;Wk]^T   (A = x-half of acomb, lda 4096)
  gemm_logits<<<dim3(64, 2), 256, 0, stream>>>(
      acomb + 2048, wqkb, logits, 4096, 256, 2048);

  // q/k/gf (+ rms accumulator zero)
  qk_post_kernel<<<dim3(8192), 64, 0, stream>>>(logits, qbuf, kbuf, gfbuf, rmsbuf);

  // GLA -> o (bf16, into acomb[:, 0:2048]) + rms partial sums
  gla_kernel<<<dim3(64, 2, 2), 256, 0, stream>>>(qbuf, kbuf, gfbuf, xbT, acomb, rmsbuf);

  // go = [o|x] @ [Wog|Wig]^T (K=4096); gated = RMSNorm(o)*g * swish(go)
  gemm256<1><<<dim3(256), 512, 0, stream>>>(
      acomb, wcomb, nullptr, gatedb, acomb, rmsbuf, gnw, 2048, 4096, 4096);

  // out = gated @ Wo^T
  gemm256<2><<<dim3(256), 512, 0, stream>>>(
      gatedb, wob, out, nullptr, nullptr, nullptr, nullptr, 2048, 2048, 2048);

  (void)in_sizes; (void)n_in; (void)out_size; (void)ws_size;
}

// Round 5
// 436.726 us; speedup vs baseline: 1.0838x; 1.0188x over previous
//
#include <hip/hip_runtime.h>
#include <hip/hip_bf16.h>

typedef __hip_bfloat16 bf16;
typedef __bf16 bf16x8 __attribute__((ext_vector_type(8)));
typedef float f32x4 __attribute__((ext_vector_type(4)));

// async global->LDS, 16B per lane. LDS dest = wave-uniform base + lane*16.
__device__ __forceinline__ void async16(void* lds_base, const void* g) {
  __builtin_amdgcn_global_load_lds(
      (const __attribute__((address_space(1))) void*)g,
      (__attribute__((address_space(3))) void*)lds_base, 16, 0, 0);
}

// ---------------------------------------------------------------------------
// f32 -> bf16 flat convert (weights)
// ---------------------------------------------------------------------------
__global__ void cvt_bf16_kernel(const float* __restrict__ s, bf16* __restrict__ d, int n4) {
  const int i = blockIdx.x * 256 + threadIdx.x;
  if (i >= n4) return;
  const float4 v = ((const float4*)s)[i];
  bf16 h0 = __float2bfloat16(v.x), h1 = __float2bfloat16(v.y);
  bf16 h2 = __float2bfloat16(v.z), h3 = __float2bfloat16(v.w);
  ushort4 o;
  o.x = *(unsigned short*)&h0; o.y = *(unsigned short*)&h1;
  o.z = *(unsigned short*)&h2; o.w = *(unsigned short*)&h3;
  *(ushort4*)((unsigned short*)d + (size_t)i * 4) = o;
}

// f32 [2048][2048] -> bf16 into rows of stride 4096 (for [Wog|Wig] K-merge)
__global__ void cvt_bf16_strided(const float* __restrict__ s, bf16* __restrict__ d, int n4) {
  const int i = blockIdx.x * 256 + threadIdx.x;
  if (i >= n4) return;
  const int row = i >> 9;          // 512 float4 per 2048-col row
  const int col4 = i & 511;
  const float4 v = ((const float4*)s)[i];
  bf16 h0 = __float2bfloat16(v.x), h1 = __float2bfloat16(v.y);
  bf16 h2 = __float2bfloat16(v.z), h3 = __float2bfloat16(v.w);
  ushort4 o;
  o.x = *(unsigned short*)&h0; o.y = *(unsigned short*)&h1;
  o.z = *(unsigned short*)&h2; o.w = *(unsigned short*)&h3;
  *(ushort4*)((unsigned short*)d + (size_t)row * 4096 + col4 * 4) = o;
}

// ---------------------------------------------------------------------------
// x (B,L,H) fp32 -> comb[.., 2048..4095] bf16 (A-matrix K-merge half)
//                 + xbT (B,H,L) bf16 (for GLA V-frags). Vectorized 16B/8B.
// ---------------------------------------------------------------------------
__global__ __launch_bounds__(256) void convert_x_kernel(
    const float* __restrict__ x, bf16* __restrict__ comb, bf16* __restrict__ xbT) {
  __shared__ float tile[64][65];
  const int b = blockIdx.z;
  const int l0 = blockIdx.x * 64, d0 = blockIdx.y * 64;
  const int t = threadIdx.x;
  const int c4 = (t & 15) * 4, r = t >> 4;  // r 0..15
  const size_t base = ((size_t)b * 4096 + l0) * 2048 + d0;
#pragma unroll
  for (int i = 0; i < 4; ++i) {
    const int row = i * 16 + r;
    const float4 v = *(const float4*)(x + base + (size_t)row * 2048 + c4);
    tile[row][c4 + 0] = v.x; tile[row][c4 + 1] = v.y;
    tile[row][c4 + 2] = v.z; tile[row][c4 + 3] = v.w;
    bf16 h0 = __float2bfloat16(v.x), h1 = __float2bfloat16(v.y);
    bf16 h2 = __float2bfloat16(v.z), h3 = __float2bfloat16(v.w);
    ushort4 o;
    o.x = *(unsigned short*)&h0; o.y = *(unsigned short*)&h1;
    o.z = *(unsigned short*)&h2; o.w = *(unsigned short*)&h3;
    *(ushort4*)(comb + ((size_t)(b * 4096 + l0 + row)) * 4096 + 2048 + d0 + c4) = o;
  }
  __syncthreads();
#pragma unroll
  for (int i = 0; i < 4; ++i) {
    const int d = i * 16 + r;
    bf16 h0 = __float2bfloat16(tile[c4 + 0][d]);
    bf16 h1 = __float2bfloat16(tile[c4 + 1][d]);
    bf16 h2 = __float2bfloat16(tile[c4 + 2][d]);
    bf16 h3 = __float2bfloat16(tile[c4 + 3][d]);
    ushort4 o;
    o.x = *(unsigned short*)&h0; o.y = *(unsigned short*)&h1;
    o.z = *(unsigned short*)&h2; o.w = *(unsigned short*)&h3;
    *(ushort4*)(xbT + ((size_t)(b * 2048 + d0 + d)) * 4096 + l0 + c4) = o;
  }
}

// ---------------------------------------------------------------------------
// m97-style bf16 GEMM for the small logits GEMM (N=256). lda-strided A.
// ---------------------------------------------------------------------------
__global__ __launch_bounds__(256, 2) void gemm_logits(
    const bf16* __restrict__ A, const bf16* __restrict__ B,
    float* __restrict__ outf, int lda, int N, int K) {
  __shared__ bf16 lA[128 * 32];
  __shared__ bf16 lB[128 * 32];
  const int tid = threadIdx.x;
  const int lane = tid & 63, wave = tid >> 6;
  const int l15 = lane & 15, l4 = lane >> 4;
  const int bm = blockIdx.x * 128, bn = blockIdx.y * 128;
  const int wm = (wave & 1) * 64, wn = (wave >> 1) * 64;
  const int srow = tid >> 2;
  const int skc = (tid & 3) * 8;

  const f32x4 fz = {0.f, 0.f, 0.f, 0.f};
  f32x4 acc[4][4];
#pragma unroll
  for (int i = 0; i < 4; ++i)
#pragma unroll
    for (int j = 0; j < 4; ++j) acc[i][j] = fz;

  bf16* lAu  = lA + wave * 512;
  bf16* lAu2 = lA + 2048 + wave * 512;
  bf16* lBu  = lB + wave * 512;
  bf16* lBu2 = lB + 2048 + wave * 512;

  const bf16* gA0 = A + (size_t)(bm + srow) * lda + skc;
  const bf16* gA1 = A + (size_t)(bm + srow + 64) * lda + skc;
  const bf16* gB0 = B + (size_t)(bn + srow) * K + skc;
  const bf16* gB1 = B + (size_t)(bn + srow + 64) * K + skc;
  for (int k0 = 0; k0 < K; k0 += 32) {
    __syncthreads();
    async16(lAu, gA0 + k0);
    async16(lAu2, gA1 + k0);
    async16(lBu, gB0 + k0);
    async16(lBu2, gB1 + k0);
    __syncthreads();
    bf16x8 af[4], bfv[4];
#pragma unroll
    for (int mt = 0; mt < 4; ++mt)
      af[mt] = *(const bf16x8*)(lA + (wm + mt * 16 + l15) * 32 + l4 * 8);
#pragma unroll
    for (int nt = 0; nt < 4; ++nt)
      bfv[nt] = *(const bf16x8*)(lB + (wn + nt * 16 + l15) * 32 + l4 * 8);
#pragma unroll
    for (int mt = 0; mt < 4; ++mt)
#pragma unroll
      for (int nt = 0; nt < 4; ++nt)
        acc[mt][nt] = __builtin_amdgcn_mfma_f32_16x16x32_bf16(af[mt], bfv[nt], acc[mt][nt], 0, 0, 0);
  }

#pragma unroll
  for (int mt = 0; mt < 4; ++mt)
#pragma unroll
    for (int r = 0; r < 4; ++r) {
      const int gr = bm + wm + mt * 16 + l4 * 4 + r;
#pragma unroll
      for (int nt = 0; nt < 4; ++nt) {
        const int gc = bn + wn + nt * 16 + l15;
        outf[(size_t)gr * N + gc] = acc[mt][nt][r];
      }
    }
}

// ---------------------------------------------------------------------------
// 256x256-tile bf16 GEMM, read-ahead pipeline, SINGLE barrier per phase
// (4/tile; all hazards closed by counted lgkm/vmcnt + phase-end barrier),
// precomputed LDS base pointers (ds_read offset:N folding, no per-read VALU).
// T1 XCD-swizzle + T2 LDS XOR-swizzle + T5 setprio. K = 64*NT (2048/4096).
// MODE 1: RMSNorm-gate-swish epilogue -> bf16.  MODE 2: fp32 out.
// 512 threads = 8 waves (2M x 4N); per-wave out 128x64; BK=64; LDS 128 KiB.
// ---------------------------------------------------------------------------
#define QMFMA(AF, BF, MH, NH)                                               \
  do {                                                                      \
    __builtin_amdgcn_s_setprio(1);                                          \
    _Pragma("unroll") for (int ks_ = 0; ks_ < 2; ++ks_) {                   \
      _Pragma("unroll") for (int mt_ = 0; mt_ < 4; ++mt_) {                 \
        _Pragma("unroll") for (int nt_ = 0; nt_ < 2; ++nt_)                 \
            acc[(MH) * 4 + mt_][(NH) * 2 + nt_] =                           \
                __builtin_amdgcn_mfma_f32_16x16x32_bf16(                    \
                    AF[mt_][ks_], BF[nt_][ks_],                             \
                    acc[(MH) * 4 + mt_][(NH) * 2 + nt_], 0, 0, 0);          \
      }                                                                     \
    }                                                                       \
    __builtin_amdgcn_s_setprio(0);                                          \
  } while (0)

// 8 ds_read_b128 from precomputed bases + compile-time offsets
#define READA(AF, PK0, PK1, MH)                                             \
  do {                                                                      \
    _Pragma("unroll") for (int mt_ = 0; mt_ < 4; ++mt_) {                   \
      AF[mt_][0] = *(const bf16x8*)((PK0) + (MH) * 4096 + mt_ * 1024);      \
      AF[mt_][1] = *(const bf16x8*)((PK1) + (MH) * 4096 + mt_ * 1024);      \
    }                                                                       \
  } while (0)

// 4 ds_read_b128
#define READB(BF, PK0, PK1, NH)                                             \
  do {                                                                      \
    _Pragma("unroll") for (int nt_ = 0; nt_ < 2; ++nt_) {                   \
      BF[nt_][0] = *(const bf16x8*)((PK0) + (NH) * 2048 + nt_ * 1024);      \
      BF[nt_][1] = *(const bf16x8*)((PK1) + (NH) * 2048 + nt_ * 1024);      \
    }                                                                       \
  } while (0)

template <int MODE>
__global__ __launch_bounds__(512, 2) void gemm256(
    const bf16* __restrict__ A, const bf16* __restrict__ B,
    float* __restrict__ outf, bf16* __restrict__ outb,
    const bf16* __restrict__ o_in, const float* __restrict__ rmssum,
    const float* __restrict__ gnw, int N, int K, int ostr) {
  __shared__ bf16 lA[2][16384];  // [buf][half*8192 + row*64 + col]
  __shared__ bf16 lB[2][16384];
  const int tid = threadIdx.x;
  const int lane = tid & 63;
  const int wave = tid >> 6;
  const int wmi = wave >> 2;   // 0..1  (M wave index)
  const int wni = wave & 3;    // 0..3  (N wave index)
  const int l15 = lane & 15, l4 = lane >> 4;
  const int axor = l15 & 7;

  // T1: bijective XCD swizzle (grid = 256 blocks, % 8 == 0)
  const int nwg = gridDim.x;
  const int cpx = nwg >> 3;
  int wg = blockIdx.x;
  wg = (wg & 7) * cpx + (wg >> 3);
  const int NBN = N >> 8;
  const int bm = (wg / NBN) * 256;
  const int bn = (wg % NBN) * 256;

  // staging: chunk c = tid -> (row = tid>>3, slot = tid&7); global source
  // pre-swizzled (slot ^ row&7) so linear LDS dest + XOR read = identity.
  const int srow = tid >> 3;
  const int scol = ((tid & 7) ^ (srow & 7)) * 8;
  const size_t goff = (size_t)srow * K + scol;
  const int NT = K >> 6;

  const bf16* Ab = A + (size_t)bm * K + goff;
  const bf16* Bb = B + (size_t)bn * K + goff;

  auto stageA = [&](int kt, int h, int buf) {
    const int t = (kt < NT) ? kt : (NT - 1);  // tail: dummy re-stage (same bytes)
    const bf16* g = Ab + (size_t)h * 128 * K + t * 64;
    bf16* d = &lA[buf][h * 8192] + tid * 8;
    async16(d, g);
    async16(d + 4096, g + (size_t)64 * K);
  };
  auto stageB = [&](int kt, int h, int buf) {
    const int t = (kt < NT) ? kt : (NT - 1);
    const bf16* g = Bb + (size_t)h * 128 * K + t * 64;
    bf16* d = &lB[buf][h * 8192] + tid * 8;
    async16(d, g);
    async16(d + 4096, g + (size_t)64 * K);
  };

  // precomputed LDS read bases: col(ks) = ((ks*4)^(axor&4))*8 + (l4^(axor&3))*8
  const int cK0 = ((l4 ^ (axor & 3)) * 8) + ((axor & 4) ? 32 : 0);
  const int cK1 = ((l4 ^ (axor & 3)) * 8) + ((axor & 4) ? 0 : 32);
  const bf16* pA00 = &lA[0][wmi * 8192 + l15 * 64 + cK0];  // [buf0][ks0]
  const bf16* pA01 = &lA[0][wmi * 8192 + l15 * 64 + cK1];  // [buf0][ks1]
  const bf16* pA10 = pA00 + 16384;                          // [buf1][ks0]
  const bf16* pA11 = pA01 + 16384;                          // [buf1][ks1]
  const int bBo = (wni >> 1) * 8192 + ((wni & 1) * 64 + l15) * 64;
  const bf16* pB00 = &lB[0][bBo + cK0];
  const bf16* pB01 = &lB[0][bBo + cK1];
  const bf16* pB10 = pB00 + 16384;
  const bf16* pB11 = pB01 + 16384;

  const f32x4 fz = {0.f, 0.f, 0.f, 0.f};
  f32x4 acc[8][4];
#pragma unroll
  for (int i = 0; i < 8; ++i)
#pragma unroll
    for (int j = 0; j < 4; ++j) acc[i][j] = fz;

  // fragment sets (loop-carried; read one phase ahead of use)
  bf16x8 aH0[4][2], aH1[4][2], b0[2][2], b1[2][2];

  // ---- prologue: stage tile0 fully + tile1 (A1h0, B1h0, B1h1, A1h1).
  stageA(0, 0, 0); stageA(0, 1, 0); stageB(0, 0, 0); stageB(0, 1, 0);
  stageA(1, 0, 1); stageB(1, 0, 1); stageB(1, 1, 1); stageA(1, 1, 1);
  asm volatile("s_waitcnt vmcnt(8)" ::: "memory");   // tile0 resident
  __builtin_amdgcn_s_barrier();
  // pre-read ph1(0) fragments (drained by ph1's lgkmcnt(4))
  READA(aH0, pA00, pA01, 0);
  READB(b0, pB00, pB01, 0);
  __builtin_amdgcn_sched_barrier(0);

  auto ktile = [&](int kt, int cur,
                   const bf16* pAc0, const bf16* pAc1,
                   const bf16* pAn0, const bf16* pAn1,
                   const bf16* pBc0, const bf16* pBc1,
                   const bf16* pBn0, const bf16* pBn1) {
    // -- ph1: MFMA Q(0,0)=aH0*b0 ; read b1 <- B(kt)h1 (cur)
    READB(b1, pBc0, pBc1, 1);
    __builtin_amdgcn_sched_barrier(0);
    asm volatile("s_waitcnt lgkmcnt(4)" ::: "memory");
    __builtin_amdgcn_sched_barrier(0);
    QMFMA(aH0, b0, 0, 0);
    asm volatile("s_waitcnt vmcnt(8)" ::: "memory");
    __builtin_amdgcn_s_barrier();
    // -- ph2: MFMA Q(0,1)=aH0*b1 ; read aH1 <- A(kt)h1 (cur); stage A(kt+2)h0
    READA(aH1, pAc0, pAc1, 1);
    stageA(kt + 2, 0, cur);
    __builtin_amdgcn_sched_barrier(0);
    asm volatile("s_waitcnt lgkmcnt(8)" ::: "memory");
    __builtin_amdgcn_sched_barrier(0);
    QMFMA(aH0, b1, 0, 1);
    asm volatile("s_waitcnt vmcnt(8)" ::: "memory");
    __builtin_amdgcn_s_barrier();
    // -- ph3: MFMA Q(1,0)=aH1*b0 ; read aH0 <- A(kt+1)h0 (nxt); stage B(kt+2)
    READA(aH0, pAn0, pAn1, 0);
    stageB(kt + 2, 0, cur);
    stageB(kt + 2, 1, cur);
    __builtin_amdgcn_sched_barrier(0);
    asm volatile("s_waitcnt lgkmcnt(8)" ::: "memory");
    __builtin_amdgcn_sched_barrier(0);
    QMFMA(aH1, b0, 1, 0);
    asm volatile("s_waitcnt vmcnt(10)" ::: "memory");
    __builtin_amdgcn_s_barrier();
    // -- ph4: MFMA Q(1,1)=aH1*b1 ; read b0 <- B(kt+1)h0 (nxt); stage A(kt+2)h1
    READB(b0, pBn0, pBn1, 0);
    stageA(kt + 2, 1, cur);
    __builtin_amdgcn_sched_barrier(0);
    asm volatile("s_waitcnt lgkmcnt(12)" ::: "memory");
    __builtin_amdgcn_sched_barrier(0);
    QMFMA(aH1, b1, 1, 1);
    asm volatile("s_waitcnt vmcnt(10)" ::: "memory");
    __builtin_amdgcn_s_barrier();
  };

  for (int kt = 0; kt < NT; kt += 2) {  // NT even (32 or 64)
    ktile(kt,     0, pA00, pA01, pA10, pA11, pB00, pB01, pB10, pB11);
    ktile(kt + 1, 1, pA10, pA11, pA00, pA01, pB10, pB11, pB00, pB01);
  }
  asm volatile("s_waitcnt vmcnt(0) lgkmcnt(0)" ::: "memory");
  __builtin_amdgcn_s_barrier();

  // ---- epilogue
#pragma unroll
  for (int i = 0; i < 8; ++i) {
#pragma unroll
    for (int r = 0; r < 4; ++r) {
      const int gr = bm + wmi * 128 + i * 16 + l4 * 4 + r;
      float rinv = 0.f;
      if (MODE == 1) rinv = rsqrtf(rmssum[gr] * (1.f / 2048.f) + 1e-5f);
#pragma unroll
      for (int j = 0; j < 4; ++j) {
        const int gc = bn + wni * 64 + j * 16 + l15;
        const float v = acc[i][j][r];
        if (MODE == 1) {
          const float o = (float)o_in[(size_t)gr * ostr + gc];
          const float on = o * rinv * gnw[gc];
          const float sw = v / (1.f + __expf(-v));   // go*sigmoid(go)
          outb[(size_t)gr * N + gc] = __float2bfloat16(on * sw);
        } else {
          outf[(size_t)gr * N + gc] = v;
        }
      }
    }
  }
}

// ---------------------------------------------------------------------------
// per-row: q = softmax(logits[0:128]), k = sigmoid(logits[128:256]),
// gf = log_sigmoid(-k) = -log(1+exp(k)).  One wave per row. Also zeroes
// the per-row RMS partial-sum accumulator consumed later.
// ---------------------------------------------------------------------------
__global__ __launch_bounds__(64) void qk_post_kernel(
    const float* __restrict__ logits, bf16* __restrict__ qb,
    bf16* __restrict__ kb, float* __restrict__ gfl, float* __restrict__ rmssum) {
  const int row = blockIdx.x;
  const int t = threadIdx.x;
  if (t == 0) rmssum[row] = 0.f;
  const float* lr = logits + (size_t)row * 256;
  float a0 = lr[t], a1 = lr[t + 64];
  float m = fmaxf(a0, a1);
#pragma unroll
  for (int s = 32; s; s >>= 1) m = fmaxf(m, __shfl_xor(m, s));
  float e0 = __expf(a0 - m), e1 = __expf(a1 - m);
  float sum = e0 + e1;
#pragma unroll
  for (int s = 32; s; s >>= 1) sum += __shfl_xor(sum, s);
  const float inv = 1.f / sum;
  qb[(size_t)row * 128 + t]      = __float2bfloat16(e0 * inv);
  qb[(size_t)row * 128 + t + 64] = __float2bfloat16(e1 * inv);
  float b0 = lr[128 + t], b1 = lr[128 + t + 64];
  float k0 = 1.f / (1.f + __expf(-b0));
  float k1 = 1.f / (1.f + __expf(-b1));
  kb[(size_t)row * 128 + t]      = __float2bfloat16(k0);
  kb[(size_t)row * 128 + t + 64] = __float2bfloat16(k1);
  gfl[(size_t)row * 128 + t]      = -log1pf(__expf(k0));
  gfl[(size_t)row * 128 + t + 64] = -log1pf(__expf(k1));
}

// ---------------------------------------------------------------------------
// GLA sliding-window kernel. Block = (chunk, batch, dv-half); 64 out rows,
// 1024 of 2048 dv columns. ob stride 4096 (into acomb[:, 0:2048]).
// ---------------------------------------------------------------------------
__global__ __launch_bounds__(256, 2) void gla_kernel(
    const bf16* __restrict__ qb, const bf16* __restrict__ kb,
    const float* __restrict__ gfl, const bf16* __restrict__ xbT,
    bf16* __restrict__ ob, float* __restrict__ rmssum) {
  __shared__ bf16 sF1[64][136];   // q*e^{Bi-M}; later reused as masked A[i][jw]
  __shared__ bf16 sF2[128][136];  // rows 0..63 prev-chunk, 64..127 current
  __shared__ float sM[128];
  __shared__ float rowsq[64];
  const int tid = threadIdx.x;
  const int lane = tid & 63, wave = tid >> 6;
  const int l15 = lane & 15, l4 = lane >> 4;
  const int chunk = blockIdx.x, b = blockIdx.y, z = blockIdx.z;
  const int row0 = b * 4096 + chunk * 64;

  if (tid < 64) rowsq[tid] = 0.f;

  if (tid < 128) {
    float s = 0.f;
    for (int i = 0; i <= 32; ++i) s += gfl[(size_t)(row0 + i) * 128 + tid];
    sM[tid] = s;
  }
  __syncthreads();

  if (tid < 128) {
    const int d = tid;
    const float M = sM[d];
    float bi = 0.f;
    for (int i = 0; i < 64; ++i) {
      bi += gfl[(size_t)(row0 + i) * 128 + d];
      const float q = (float)qb[(size_t)(row0 + i) * 128 + d];
      const float k = (float)kb[(size_t)(row0 + i) * 128 + d];
      sF1[i][d]      = __float2bfloat16(q * __expf(bi - M));
      sF2[64 + i][d] = __float2bfloat16(k * __expf(M - bi));
    }
  } else {
    const int d = tid - 128;
    if (chunk == 0) {
      for (int j = 0; j < 64; ++j) sF2[j][d] = __float2bfloat16(0.f);
    } else {
      const float M = sM[d];
      float bw = 0.f;
      for (int j = 63; j >= 0; --j) {
        const float k = (float)kb[(size_t)(row0 - 64 + j) * 128 + d];
        sF2[j][d] = __float2bfloat16(k * __expf(M - bw));
        bw -= gfl[(size_t)(row0 - 64 + j) * 128 + d];
      }
    }
  }
  __syncthreads();

  const f32x4 fz = {0.f, 0.f, 0.f, 0.f};
  {
    f32x4 sacc[4][2];
#pragma unroll
    for (int mt = 0; mt < 4; ++mt) { sacc[mt][0] = fz; sacc[mt][1] = fz; }
    bf16x8 f1[4][4];
#pragma unroll
    for (int kt = 0; kt < 4; ++kt)
#pragma unroll
      for (int mt = 0; mt < 4; ++mt)
        f1[kt][mt] = *(const bf16x8*)(&sF1[mt * 16 + l15][kt * 32 + l4 * 8]);
#pragma unroll
    for (int nt = 0; nt < 2; ++nt)
#pragma unroll
      for (int kt = 0; kt < 4; ++kt) {
        const bf16x8 f2 = *(const bf16x8*)(&sF2[wave * 32 + nt * 16 + l15][kt * 32 + l4 * 8]);
#pragma unroll
        for (int mt = 0; mt < 4; ++mt)
          sacc[mt][nt] = __builtin_amdgcn_mfma_f32_16x16x32_bf16(f1[kt][mt], f2, sacc[mt][nt], 0, 0, 0);
      }
    __syncthreads();
#pragma unroll
    for (int mt = 0; mt < 4; ++mt)
#pragma unroll
      for (int nt = 0; nt < 2; ++nt)
#pragma unroll
        for (int r = 0; r < 4; ++r) {
          const int i = mt * 16 + l4 * 4 + r;
          const int jw = wave * 32 + nt * 16 + l15;
          const bool ok = (jw < 64) || (jw - 64 <= i);
          sF1[i][jw] = __float2bfloat16(ok ? sacc[mt][nt][r] : 0.f);
        }
    __syncthreads();
  }

  bf16x8 av[4][4];
#pragma unroll
  for (int kt = 0; kt < 4; ++kt)
#pragma unroll
    for (int mt = 0; mt < 4; ++mt)
      av[kt][mt] = *(const bf16x8*)(&sF1[mt * 16 + l15][kt * 32 + l4 * 8]);

  float rs[4][4];
#pragma unroll
  for (int a = 0; a < 4; ++a)
#pragma unroll
    for (int r2 = 0; r2 < 4; ++r2) rs[a][r2] = 0.f;

  const int lwb = chunk * 64 - 64;
  for (int dt = z * 4; dt < z * 4 + 4; ++dt) {
    const int c0 = dt * 256 + wave * 64;
    f32x4 oacc[4][4];
#pragma unroll
    for (int mt = 0; mt < 4; ++mt)
#pragma unroll
      for (int nt = 0; nt < 4; ++nt) oacc[mt][nt] = fz;
#pragma unroll
    for (int kt = 0; kt < 4; ++kt)
#pragma unroll
      for (int nt = 0; nt < 4; ++nt) {
        const int dv = c0 + nt * 16 + l15;
        int lw = lwb + kt * 32 + l4 * 8;
        if (lw < 0) lw = 0;  // chunk 0 prev-half: A==0, any valid addr is fine
        const bf16x8 vv = *(const bf16x8*)(xbT + ((size_t)b * 2048 + dv) * 4096 + lw);
#pragma unroll
        for (int mt = 0; mt < 4; ++mt)
          oacc[mt][nt] = __builtin_amdgcn_mfma_f32_16x16x32_bf16(av[kt][mt], vv, oacc[mt][nt], 0, 0, 0);
      }
#pragma unroll
    for (int mt = 0; mt < 4; ++mt)
#pragma unroll
      for (int r = 0; r < 4; ++r) {
        const int i = mt * 16 + l4 * 4 + r;
#pragma unroll
        for (int nt = 0; nt < 4; ++nt) {
          const float v = oacc[mt][nt][r];
          ob[(size_t)(row0 + i) * 4096 + (c0 + nt * 16 + l15)] = __float2bfloat16(v);
          rs[mt][r] += v * v;
        }
      }
  }

#pragma unroll
  for (int mt = 0; mt < 4; ++mt)
#pragma unroll
    for (int r = 0; r < 4; ++r) {
      float v = rs[mt][r];
      v += __shfl_xor(v, 1); v += __shfl_xor(v, 2);
      v += __shfl_xor(v, 4); v += __shfl_xor(v, 8);
      if (l15 == 0) atomicAdd(&rowsq[mt * 16 + l4 * 4 + r], v);
    }
  __syncthreads();
  if (tid < 64)
    atomicAdd(&rmssum[row0 + tid], rowsq[tid]);
}

// ---------------------------------------------------------------------------
extern "C" void kernel_launch(void* const* d_in, const int* in_sizes, int n_in,
                              void* d_out, int out_size, void* d_ws, size_t ws_size,
                              hipStream_t stream) {
  const float* x   = (const float*)d_in[0];
  const float* Wq  = (const float*)d_in[1];
  const float* Wk  = (const float*)d_in[2];
  const float* Wog = (const float*)d_in[3];
  const float* Wig = (const float*)d_in[4];
  const float* Wo  = (const float*)d_in[5];
  const float* gnw = (const float*)d_in[6];
  float* out = (float*)d_out;

  char* w = (char*)d_ws;
  auto alloc = [&](size_t bytes) {
    char* p = w;
    w += (bytes + 255) & ~(size_t)255;
    return p;
  };
  bf16*  wqkb   = (bf16*)alloc((size_t)256 * 2048 * 2);
  bf16*  wcomb  = (bf16*)alloc((size_t)2048 * 4096 * 2);   // [Wog | Wig]
  bf16*  wob    = (bf16*)alloc((size_t)2048 * 2048 * 2);
  bf16*  acomb  = (bf16*)alloc((size_t)8192 * 4096 * 2);   // [o | x] per row
  bf16*  xbT    = (bf16*)alloc((size_t)8192 * 2048 * 2);
  float* logits = (float*)alloc((size_t)8192 * 256 * 4);
  bf16*  qbuf   = (bf16*)alloc((size_t)8192 * 128 * 2);
  bf16*  kbuf   = (bf16*)alloc((size_t)8192 * 128 * 2);
  float* gfbuf  = (float*)alloc((size_t)8192 * 128 * 4);
  float* rmsbuf = (float*)alloc((size_t)8192 * 4);
  bf16*  gatedb = xbT;  // xbT dead after gla_kernel -> reuse for gated

  // weights -> bf16
  cvt_bf16_kernel<<<dim3((65536 + 255) / 256), 256, 0, stream>>>(Wq, wqkb, 65536);
  cvt_bf16_kernel<<<dim3((65536 + 255) / 256), 256, 0, stream>>>(Wk, wqkb + 262144, 65536);
  cvt_bf16_strided<<<dim3((1048576 + 255) / 256), 256, 0, stream>>>(Wog, wcomb, 1048576);
  cvt_bf16_strided<<<dim3((1048576 + 255) / 256), 256, 0, stream>>>(Wig, wcomb + 2048, 1048576);
  cvt_bf16_kernel<<<dim3((1048576 + 255) / 256), 256, 0, stream>>>(Wo, wob, 1048576);

  // x -> acomb[:, 2048:4096] + xbT
  convert_x_kernel<<<dim3(64, 32, 2), 256, 0, stream>>>(x, acomb, xbT);

  // logits = x @ [Wq;Wk]^T   (A = x-half of acomb, lda 4096)
  gemm_logits<<<dim3(64, 2), 256, 0, stream>>>(
      acomb + 2048, wqkb, logits, 4096, 256, 2048);

  // q/k/gf (+ rms accumulator zero)
  qk_post_kernel<<<dim3(8192), 64, 0, stream>>>(logits, qbuf, kbuf, gfbuf, rmsbuf);

  // GLA -> o (bf16, into acomb[:, 0:2048]) + rms partial sums
  gla_kernel<<<dim3(64, 2, 2), 256, 0, stream>>>(qbuf, kbuf, gfbuf, xbT, acomb, rmsbuf);

  // go = [o|x] @ [Wog|Wig]^T (K=4096); gated = RMSNorm(o)*g * swish(go)
  gemm256<1><<<dim3(256), 512, 0, stream>>>(
      acomb, wcomb, nullptr, gatedb, acomb, rmsbuf, gnw, 2048, 4096, 4096);

  // out = gated @ Wo^T
  gemm256<2><<<dim3(256), 512, 0, stream>>>(
      gatedb, wob, out, nullptr, nullptr, nullptr, nullptr, 2048, 2048, 2048);

  (void)in_sizes; (void)n_in; (void)out_size; (void)ws_size;
}

// Round 6
// 419.285 us; speedup vs baseline: 1.1289x; 1.0416x over previous
//
#include <hip/hip_runtime.h>
#include <hip/hip_bf16.h>

typedef __hip_bfloat16 bf16;
typedef __bf16 bf16x8 __attribute__((ext_vector_type(8)));
typedef float f32x4 __attribute__((ext_vector_type(4)));

// async global->LDS, 16B per lane. LDS dest = wave-uniform base + lane*16.
__device__ __forceinline__ void async16(void* lds_base, const void* g) {
  __builtin_amdgcn_global_load_lds(
      (const __attribute__((address_space(1))) void*)g,
      (__attribute__((address_space(3))) void*)lds_base, 16, 0, 0);
}

// ---------------------------------------------------------------------------
// f32 -> bf16 flat convert (weights)
// ---------------------------------------------------------------------------
__global__ void cvt_bf16_kernel(const float* __restrict__ s, bf16* __restrict__ d, int n4) {
  const int i = blockIdx.x * 256 + threadIdx.x;
  if (i >= n4) return;
  const float4 v = ((const float4*)s)[i];
  bf16 h0 = __float2bfloat16(v.x), h1 = __float2bfloat16(v.y);
  bf16 h2 = __float2bfloat16(v.z), h3 = __float2bfloat16(v.w);
  ushort4 o;
  o.x = *(unsigned short*)&h0; o.y = *(unsigned short*)&h1;
  o.z = *(unsigned short*)&h2; o.w = *(unsigned short*)&h3;
  *(ushort4*)((unsigned short*)d + (size_t)i * 4) = o;
}

// f32 [2048][2048] -> bf16 into rows of stride 4096 (for [Wog|Wig] K-merge)
__global__ void cvt_bf16_strided(const float* __restrict__ s, bf16* __restrict__ d, int n4) {
  const int i = blockIdx.x * 256 + threadIdx.x;
  if (i >= n4) return;
  const int row = i >> 9;          // 512 float4 per 2048-col row
  const int col4 = i & 511;
  const float4 v = ((const float4*)s)[i];
  bf16 h0 = __float2bfloat16(v.x), h1 = __float2bfloat16(v.y);
  bf16 h2 = __float2bfloat16(v.z), h3 = __float2bfloat16(v.w);
  ushort4 o;
  o.x = *(unsigned short*)&h0; o.y = *(unsigned short*)&h1;
  o.z = *(unsigned short*)&h2; o.w = *(unsigned short*)&h3;
  *(ushort4*)((unsigned short*)d + (size_t)row * 4096 + col4 * 4) = o;
}

// ---------------------------------------------------------------------------
// x (B,L,H) fp32 -> comb[.., 2048..4095] bf16 (A-matrix K-merge half)
//                 + xbT (B,H,L) bf16 (for GLA V-frags). Vectorized 16B/8B.
// ---------------------------------------------------------------------------
__global__ __launch_bounds__(256) void convert_x_kernel(
    const float* __restrict__ x, bf16* __restrict__ comb, bf16* __restrict__ xbT) {
  __shared__ float tile[64][65];
  const int b = blockIdx.z;
  const int l0 = blockIdx.x * 64, d0 = blockIdx.y * 64;
  const int t = threadIdx.x;
  const int c4 = (t & 15) * 4, r = t >> 4;  // r 0..15
  const size_t base = ((size_t)b * 4096 + l0) * 2048 + d0;
#pragma unroll
  for (int i = 0; i < 4; ++i) {
    const int row = i * 16 + r;
    const float4 v = *(const float4*)(x + base + (size_t)row * 2048 + c4);
    tile[row][c4 + 0] = v.x; tile[row][c4 + 1] = v.y;
    tile[row][c4 + 2] = v.z; tile[row][c4 + 3] = v.w;
    bf16 h0 = __float2bfloat16(v.x), h1 = __float2bfloat16(v.y);
    bf16 h2 = __float2bfloat16(v.z), h3 = __float2bfloat16(v.w);
    ushort4 o;
    o.x = *(unsigned short*)&h0; o.y = *(unsigned short*)&h1;
    o.z = *(unsigned short*)&h2; o.w = *(unsigned short*)&h3;
    *(ushort4*)(comb + ((size_t)(b * 4096 + l0 + row)) * 4096 + 2048 + d0 + c4) = o;
  }
  __syncthreads();
#pragma unroll
  for (int i = 0; i < 4; ++i) {
    const int d = i * 16 + r;
    bf16 h0 = __float2bfloat16(tile[c4 + 0][d]);
    bf16 h1 = __float2bfloat16(tile[c4 + 1][d]);
    bf16 h2 = __float2bfloat16(tile[c4 + 2][d]);
    bf16 h3 = __float2bfloat16(tile[c4 + 3][d]);
    ushort4 o;
    o.x = *(unsigned short*)&h0; o.y = *(unsigned short*)&h1;
    o.z = *(unsigned short*)&h2; o.w = *(unsigned short*)&h3;
    *(ushort4*)(xbT + ((size_t)(b * 2048 + d0 + d)) * 4096 + l0 + c4) = o;
  }
}

// ---------------------------------------------------------------------------
// m97-style bf16 GEMM for the logits GEMM, SPLIT-K over blockIdx.z.
// z selects K-half [z*1024, z*1024+1024) and partial-output buffer.
// C_z[m,n] = sum_{k in half} A[m,k]*B[n,k]; 128x128 tile, BK=32, 256 thr.
// ---------------------------------------------------------------------------
__global__ __launch_bounds__(256, 2) void gemm_logits(
    const bf16* __restrict__ A, const bf16* __restrict__ B,
    float* __restrict__ outf, int lda, int ldb, int N, int Kloop) {
  __shared__ bf16 lA[128 * 32];
  __shared__ bf16 lB[128 * 32];
  const int tid = threadIdx.x;
  const int lane = tid & 63, wave = tid >> 6;
  const int l15 = lane & 15, l4 = lane >> 4;
  const int bm = blockIdx.x * 128, bn = blockIdx.y * 128;
  const int z = blockIdx.z;
  const int wm = (wave & 1) * 64, wn = (wave >> 1) * 64;
  const int srow = tid >> 2;
  const int skc = (tid & 3) * 8;

  A += z * Kloop;                       // K-half offset
  B += z * Kloop;
  outf += (size_t)z * 8192 * 256;       // partial buffer

  const f32x4 fz = {0.f, 0.f, 0.f, 0.f};
  f32x4 acc[4][4];
#pragma unroll
  for (int i = 0; i < 4; ++i)
#pragma unroll
    for (int j = 0; j < 4; ++j) acc[i][j] = fz;

  bf16* lAu  = lA + wave * 512;
  bf16* lAu2 = lA + 2048 + wave * 512;
  bf16* lBu  = lB + wave * 512;
  bf16* lBu2 = lB + 2048 + wave * 512;

  const bf16* gA0 = A + (size_t)(bm + srow) * lda + skc;
  const bf16* gA1 = A + (size_t)(bm + srow + 64) * lda + skc;
  const bf16* gB0 = B + (size_t)(bn + srow) * ldb + skc;
  const bf16* gB1 = B + (size_t)(bn + srow + 64) * ldb + skc;
  for (int k0 = 0; k0 < Kloop; k0 += 32) {
    __syncthreads();
    async16(lAu, gA0 + k0);
    async16(lAu2, gA1 + k0);
    async16(lBu, gB0 + k0);
    async16(lBu2, gB1 + k0);
    __syncthreads();
    bf16x8 af[4], bfv[4];
#pragma unroll
    for (int mt = 0; mt < 4; ++mt)
      af[mt] = *(const bf16x8*)(lA + (wm + mt * 16 + l15) * 32 + l4 * 8);
#pragma unroll
    for (int nt = 0; nt < 4; ++nt)
      bfv[nt] = *(const bf16x8*)(lB + (wn + nt * 16 + l15) * 32 + l4 * 8);
#pragma unroll
    for (int mt = 0; mt < 4; ++mt)
#pragma unroll
      for (int nt = 0; nt < 4; ++nt)
        acc[mt][nt] = __builtin_amdgcn_mfma_f32_16x16x32_bf16(af[mt], bfv[nt], acc[mt][nt], 0, 0, 0);
  }

#pragma unroll
  for (int mt = 0; mt < 4; ++mt)
#pragma unroll
    for (int r = 0; r < 4; ++r) {
      const int gr = bm + wm + mt * 16 + l4 * 4 + r;
#pragma unroll
      for (int nt = 0; nt < 4; ++nt) {
        const int gc = bn + wn + nt * 16 + l15;
        outf[(size_t)gr * N + gc] = acc[mt][nt][r];
      }
    }
}

// ---------------------------------------------------------------------------
// 256x256-tile bf16 GEMM, read-ahead pipeline, single barrier per phase,
// precomputed LDS bases, per-tile uniform staging offset (hoisted clamp).
// T1 XCD-swizzle + T2 LDS XOR-swizzle + T5 setprio. K = 64*NT (2048/4096).
// MODE 1: RMSNorm-gate-swish epilogue -> bf16.  MODE 2: fp32 out.
// 512 threads = 8 waves (2M x 4N); per-wave out 128x64; BK=64; LDS 128 KiB.
// ---------------------------------------------------------------------------
#define QMFMA(AF, BF, MH, NH)                                               \
  do {                                                                      \
    __builtin_amdgcn_s_setprio(1);                                          \
    _Pragma("unroll") for (int ks_ = 0; ks_ < 2; ++ks_) {                   \
      _Pragma("unroll") for (int mt_ = 0; mt_ < 4; ++mt_) {                 \
        _Pragma("unroll") for (int nt_ = 0; nt_ < 2; ++nt_)                 \
            acc[(MH) * 4 + mt_][(NH) * 2 + nt_] =                           \
                __builtin_amdgcn_mfma_f32_16x16x32_bf16(                    \
                    AF[mt_][ks_], BF[nt_][ks_],                             \
                    acc[(MH) * 4 + mt_][(NH) * 2 + nt_], 0, 0, 0);          \
      }                                                                     \
    }                                                                       \
    __builtin_amdgcn_s_setprio(0);                                          \
  } while (0)

// 8 ds_read_b128 from precomputed bases + compile-time offsets
#define READA(AF, PK0, PK1, MH)                                             \
  do {                                                                      \
    _Pragma("unroll") for (int mt_ = 0; mt_ < 4; ++mt_) {                   \
      AF[mt_][0] = *(const bf16x8*)((PK0) + (MH) * 4096 + mt_ * 1024);      \
      AF[mt_][1] = *(const bf16x8*)((PK1) + (MH) * 4096 + mt_ * 1024);      \
    }                                                                       \
  } while (0)

// 4 ds_read_b128
#define READB(BF, PK0, PK1, NH)                                             \
  do {                                                                      \
    _Pragma("unroll") for (int nt_ = 0; nt_ < 2; ++nt_) {                   \
      BF[nt_][0] = *(const bf16x8*)((PK0) + (NH) * 2048 + nt_ * 1024);      \
      BF[nt_][1] = *(const bf16x8*)((PK1) + (NH) * 2048 + nt_ * 1024);      \
    }                                                                       \
  } while (0)

template <int MODE>
__global__ __launch_bounds__(512, 2) void gemm256(
    const bf16* __restrict__ A, const bf16* __restrict__ B,
    float* __restrict__ outf, bf16* __restrict__ outb,
    const bf16* __restrict__ o_in, const float* __restrict__ rmssum,
    const float* __restrict__ gnw, int N, int K, int ostr) {
  __shared__ bf16 lA[2][16384];  // [buf][half*8192 + row*64 + col]
  __shared__ bf16 lB[2][16384];
  const int tid = threadIdx.x;
  const int lane = tid & 63;
  const int wave = tid >> 6;
  const int wmi = wave >> 2;   // 0..1  (M wave index)
  const int wni = wave & 3;    // 0..3  (N wave index)
  const int l15 = lane & 15, l4 = lane >> 4;
  const int axor = l15 & 7;

  // T1: bijective XCD swizzle (grid = 256 blocks, % 8 == 0)
  const int nwg = gridDim.x;
  const int cpx = nwg >> 3;
  int wg = blockIdx.x;
  wg = (wg & 7) * cpx + (wg >> 3);
  const int NBN = N >> 8;
  const int bm = (wg / NBN) * 256;
  const int bn = (wg % NBN) * 256;

  // staging: chunk c = tid -> (row = tid>>3, slot = tid&7); global source
  // pre-swizzled (slot ^ row&7) so linear LDS dest + XOR read = identity.
  const int srow = tid >> 3;
  const int scol = ((tid & 7) ^ (srow & 7)) * 8;
  const size_t goff = (size_t)srow * K + scol;
  const int NT = K >> 6;

  const bf16* Ab = A + (size_t)bm * K + goff;
  const bf16* Bb = B + (size_t)bn * K + goff;

  // off = element K-offset of the target tile (uniform per tile)
  auto stageA = [&](int off, int h, int buf) {
    const bf16* g = Ab + (size_t)h * 128 * K + off;
    bf16* d = &lA[buf][h * 8192] + tid * 8;
    async16(d, g);
    async16(d + 4096, g + (size_t)64 * K);
  };
  auto stageB = [&](int off, int h, int buf) {
    const bf16* g = Bb + (size_t)h * 128 * K + off;
    bf16* d = &lB[buf][h * 8192] + tid * 8;
    async16(d, g);
    async16(d + 4096, g + (size_t)64 * K);
  };

  // precomputed LDS read bases: col(ks) = ((ks*4)^(axor&4))*8 + (l4^(axor&3))*8
  const int cK0 = ((l4 ^ (axor & 3)) * 8) + ((axor & 4) ? 32 : 0);
  const int cK1 = ((l4 ^ (axor & 3)) * 8) + ((axor & 4) ? 0 : 32);
  const bf16* pA00 = &lA[0][wmi * 8192 + l15 * 64 + cK0];  // [buf0][ks0]
  const bf16* pA01 = &lA[0][wmi * 8192 + l15 * 64 + cK1];  // [buf0][ks1]
  const bf16* pA10 = pA00 + 16384;                          // [buf1][ks0]
  const bf16* pA11 = pA01 + 16384;                          // [buf1][ks1]
  const int bBo = (wni >> 1) * 8192 + ((wni & 1) * 64 + l15) * 64;
  const bf16* pB00 = &lB[0][bBo + cK0];
  const bf16* pB01 = &lB[0][bBo + cK1];
  const bf16* pB10 = pB00 + 16384;
  const bf16* pB11 = pB01 + 16384;

  const f32x4 fz = {0.f, 0.f, 0.f, 0.f};
  f32x4 acc[8][4];
#pragma unroll
  for (int i = 0; i < 8; ++i)
#pragma unroll
    for (int j = 0; j < 4; ++j) acc[i][j] = fz;

  // fragment sets (loop-carried; read one phase ahead of use)
  bf16x8 aH0[4][2], aH1[4][2], b0[2][2], b1[2][2];

  // ---- prologue: stage tile0 fully + tile1 (A1h0, B1h0, B1h1, A1h1).
  stageA(0, 0, 0); stageA(0, 1, 0); stageB(0, 0, 0); stageB(0, 1, 0);
  stageA(64, 0, 1); stageB(64, 0, 1); stageB(64, 1, 1); stageA(64, 1, 1);
  asm volatile("s_waitcnt vmcnt(8)" ::: "memory");   // tile0 resident
  __builtin_amdgcn_s_barrier();
  // pre-read ph1(0) fragments (drained by ph1's lgkmcnt(4))
  READA(aH0, pA00, pA01, 0);
  READB(b0, pB00, pB01, 0);
  __builtin_amdgcn_sched_barrier(0);

  auto ktile = [&](int kt, int cur,
                   const bf16* pAc0, const bf16* pAc1,
                   const bf16* pAn0, const bf16* pAn1,
                   const bf16* pBc0, const bf16* pBc1,
                   const bf16* pBn0, const bf16* pBn1) {
    // uniform staging K-offset for tile kt+2 (tail: dummy re-stage of last)
    const int t2 = ((kt + 2 < NT) ? (kt + 2) : (NT - 1)) * 64;
    // -- ph1: MFMA Q(0,0)=aH0*b0 ; read b1 <- B(kt)h1 (cur)
    READB(b1, pBc0, pBc1, 1);
    __builtin_amdgcn_sched_barrier(0);
    asm volatile("s_waitcnt lgkmcnt(4)" ::: "memory");
    __builtin_amdgcn_sched_barrier(0);
    QMFMA(aH0, b0, 0, 0);
    asm volatile("s_waitcnt vmcnt(8)" ::: "memory");
    __builtin_amdgcn_s_barrier();
    // -- ph2: MFMA Q(0,1)=aH0*b1 ; read aH1 <- A(kt)h1 (cur); stage A(kt+2)h0
    READA(aH1, pAc0, pAc1, 1);
    stageA(t2, 0, cur);
    __builtin_amdgcn_sched_barrier(0);
    asm volatile("s_waitcnt lgkmcnt(8)" ::: "memory");
    __builtin_amdgcn_sched_barrier(0);
    QMFMA(aH0, b1, 0, 1);
    asm volatile("s_waitcnt vmcnt(8)" ::: "memory");
    __builtin_amdgcn_s_barrier();
    // -- ph3: MFMA Q(1,0)=aH1*b0 ; read aH0 <- A(kt+1)h0 (nxt); stage B(kt+2)
    READA(aH0, pAn0, pAn1, 0);
    stageB(t2, 0, cur);
    stageB(t2, 1, cur);
    __builtin_amdgcn_sched_barrier(0);
    asm volatile("s_waitcnt lgkmcnt(8)" ::: "memory");
    __builtin_amdgcn_sched_barrier(0);
    QMFMA(aH1, b0, 1, 0);
    asm volatile("s_waitcnt vmcnt(10)" ::: "memory");
    __builtin_amdgcn_s_barrier();
    // -- ph4: MFMA Q(1,1)=aH1*b1 ; read b0 <- B(kt+1)h0 (nxt); stage A(kt+2)h1
    READB(b0, pBn0, pBn1, 0);
    stageA(t2, 1, cur);
    __builtin_amdgcn_sched_barrier(0);
    asm volatile("s_waitcnt lgkmcnt(12)" ::: "memory");
    __builtin_amdgcn_sched_barrier(0);
    QMFMA(aH1, b1, 1, 1);
    asm volatile("s_waitcnt vmcnt(10)" ::: "memory");
    __builtin_amdgcn_s_barrier();
  };

  for (int kt = 0; kt < NT; kt += 2) {  // NT even (32 or 64)
    ktile(kt,     0, pA00, pA01, pA10, pA11, pB00, pB01, pB10, pB11);
    ktile(kt + 1, 1, pA10, pA11, pA00, pA01, pB10, pB11, pB00, pB01);
  }
  asm volatile("s_waitcnt vmcnt(0) lgkmcnt(0)" ::: "memory");
  __builtin_amdgcn_s_barrier();

  // ---- epilogue
#pragma unroll
  for (int i = 0; i < 8; ++i) {
#pragma unroll
    for (int r = 0; r < 4; ++r) {
      const int gr = bm + wmi * 128 + i * 16 + l4 * 4 + r;
      float rinv = 0.f;
      if (MODE == 1) rinv = rsqrtf(rmssum[gr] * (1.f / 2048.f) + 1e-5f);
#pragma unroll
      for (int j = 0; j < 4; ++j) {
        const int gc = bn + wni * 64 + j * 16 + l15;
        const float v = acc[i][j][r];
        if (MODE == 1) {
          const float o = (float)o_in[(size_t)gr * ostr + gc];
          const float on = o * rinv * gnw[gc];
          const float sw = v / (1.f + __expf(-v));   // go*sigmoid(go)
          outb[(size_t)gr * N + gc] = __float2bfloat16(on * sw);
        } else {
          outf[(size_t)gr * N + gc] = v;
        }
      }
    }
  }
}

// ---------------------------------------------------------------------------
// per-row over SUM of two split-K logit partials:
// q = softmax(l[0:128]), k = sigmoid(l[128:256]), gf = -log1p(exp(k)).
// 4 rows per block (one wave each); zeroes the RMS partial accumulator.
// ---------------------------------------------------------------------------
__global__ __launch_bounds__(256) void qk_post_kernel(
    const float* __restrict__ l0, const float* __restrict__ l1,
    bf16* __restrict__ qb, bf16* __restrict__ kb,
    float* __restrict__ gfl, float* __restrict__ rmssum) {
  const int t = threadIdx.x & 63;
  const int row = blockIdx.x * 4 + (threadIdx.x >> 6);
  if (t == 0) rmssum[row] = 0.f;
  const float* lr0 = l0 + (size_t)row * 256;
  const float* lr1 = l1 + (size_t)row * 256;
  float a0 = lr0[t] + lr1[t];
  float a1 = lr0[t + 64] + lr1[t + 64];
  float m = fmaxf(a0, a1);
#pragma unroll
  for (int s = 32; s; s >>= 1) m = fmaxf(m, __shfl_xor(m, s));
  float e0 = __expf(a0 - m), e1 = __expf(a1 - m);
  float sum = e0 + e1;
#pragma unroll
  for (int s = 32; s; s >>= 1) sum += __shfl_xor(sum, s);
  const float inv = 1.f / sum;
  qb[(size_t)row * 128 + t]      = __float2bfloat16(e0 * inv);
  qb[(size_t)row * 128 + t + 64] = __float2bfloat16(e1 * inv);
  float b0 = lr0[128 + t] + lr1[128 + t];
  float b1 = lr0[192 + t] + lr1[192 + t];
  float k0 = 1.f / (1.f + __expf(-b0));
  float k1 = 1.f / (1.f + __expf(-b1));
  kb[(size_t)row * 128 + t]      = __float2bfloat16(k0);
  kb[(size_t)row * 128 + t + 64] = __float2bfloat16(k1);
  gfl[(size_t)row * 128 + t]      = -log1pf(__expf(k0));
  gfl[(size_t)row * 128 + t + 64] = -log1pf(__expf(k1));
}

// ---------------------------------------------------------------------------
// GLA sliding-window kernel. Block = (chunk, batch, dv-half); 64 out rows,
// 1024 of 2048 dv columns. ob stride 4096 (into acomb[:, 0:2048]).
// ---------------------------------------------------------------------------
__global__ __launch_bounds__(256, 2) void gla_kernel(
    const bf16* __restrict__ qb, const bf16* __restrict__ kb,
    const float* __restrict__ gfl, const bf16* __restrict__ xbT,
    bf16* __restrict__ ob, float* __restrict__ rmssum) {
  __shared__ bf16 sF1[64][136];   // q*e^{Bi-M}; later reused as masked A[i][jw]
  __shared__ bf16 sF2[128][136];  // rows 0..63 prev-chunk, 64..127 current
  __shared__ float sM[128];
  __shared__ float rowsq[64];
  const int tid = threadIdx.x;
  const int lane = tid & 63, wave = tid >> 6;
  const int l15 = lane & 15, l4 = lane >> 4;
  const int chunk = blockIdx.x, b = blockIdx.y, z = blockIdx.z;
  const int row0 = b * 4096 + chunk * 64;

  if (tid < 64) rowsq[tid] = 0.f;

  if (tid < 128) {
    float s = 0.f;
    for (int i = 0; i <= 32; ++i) s += gfl[(size_t)(row0 + i) * 128 + tid];
    sM[tid] = s;
  }
  __syncthreads();

  if (tid < 128) {
    const int d = tid;
    const float M = sM[d];
    float bi = 0.f;
    for (int i = 0; i < 64; ++i) {
      bi += gfl[(size_t)(row0 + i) * 128 + d];
      const float q = (float)qb[(size_t)(row0 + i) * 128 + d];
      const float k = (float)kb[(size_t)(row0 + i) * 128 + d];
      sF1[i][d]      = __float2bfloat16(q * __expf(bi - M));
      sF2[64 + i][d] = __float2bfloat16(k * __expf(M - bi));
    }
  } else {
    const int d = tid - 128;
    if (chunk == 0) {
      for (int j = 0; j < 64; ++j) sF2[j][d] = __float2bfloat16(0.f);
    } else {
      const float M = sM[d];
      float bw = 0.f;
      for (int j = 63; j >= 0; --j) {
        const float k = (float)kb[(size_t)(row0 - 64 + j) * 128 + d];
        sF2[j][d] = __float2bfloat16(k * __expf(M - bw));
        bw -= gfl[(size_t)(row0 - 64 + j) * 128 + d];
      }
    }
  }
  __syncthreads();

  const f32x4 fz = {0.f, 0.f, 0.f, 0.f};
  {
    f32x4 sacc[4][2];
#pragma unroll
    for (int mt = 0; mt < 4; ++mt) { sacc[mt][0] = fz; sacc[mt][1] = fz; }
    bf16x8 f1[4][4];
#pragma unroll
    for (int kt = 0; kt < 4; ++kt)
#pragma unroll
      for (int mt = 0; mt < 4; ++mt)
        f1[kt][mt] = *(const bf16x8*)(&sF1[mt * 16 + l15][kt * 32 + l4 * 8]);
#pragma unroll
    for (int nt = 0; nt < 2; ++nt)
#pragma unroll
      for (int kt = 0; kt < 4; ++kt) {
        const bf16x8 f2 = *(const bf16x8*)(&sF2[wave * 32 + nt * 16 + l15][kt * 32 + l4 * 8]);
#pragma unroll
        for (int mt = 0; mt < 4; ++mt)
          sacc[mt][nt] = __builtin_amdgcn_mfma_f32_16x16x32_bf16(f1[kt][mt], f2, sacc[mt][nt], 0, 0, 0);
      }
    __syncthreads();
#pragma unroll
    for (int mt = 0; mt < 4; ++mt)
#pragma unroll
      for (int nt = 0; nt < 2; ++nt)
#pragma unroll
        for (int r = 0; r < 4; ++r) {
          const int i = mt * 16 + l4 * 4 + r;
          const int jw = wave * 32 + nt * 16 + l15;
          const bool ok = (jw < 64) || (jw - 64 <= i);
          sF1[i][jw] = __float2bfloat16(ok ? sacc[mt][nt][r] : 0.f);
        }
    __syncthreads();
  }

  bf16x8 av[4][4];
#pragma unroll
  for (int kt = 0; kt < 4; ++kt)
#pragma unroll
    for (int mt = 0; mt < 4; ++mt)
      av[kt][mt] = *(const bf16x8*)(&sF1[mt * 16 + l15][kt * 32 + l4 * 8]);

  float rs[4][4];
#pragma unroll
  for (int a = 0; a < 4; ++a)
#pragma unroll
    for (int r2 = 0; r2 < 4; ++r2) rs[a][r2] = 0.f;

  const int lwb = chunk * 64 - 64;
  for (int dt = z * 4; dt < z * 4 + 4; ++dt) {
    const int c0 = dt * 256 + wave * 64;
    f32x4 oacc[4][4];
#pragma unroll
    for (int mt = 0; mt < 4; ++mt)
#pragma unroll
      for (int nt = 0; nt < 4; ++nt) oacc[mt][nt] = fz;
#pragma unroll
    for (int kt = 0; kt < 4; ++kt)
#pragma unroll
      for (int nt = 0; nt < 4; ++nt) {
        const int dv = c0 + nt * 16 + l15;
        int lw = lwb + kt * 32 + l4 * 8;
        if (lw < 0) lw = 0;  // chunk 0 prev-half: A==0, any valid addr is fine
        const bf16x8 vv = *(const bf16x8*)(xbT + ((size_t)b * 2048 + dv) * 4096 + lw);
#pragma unroll
        for (int mt = 0; mt < 4; ++mt)
          oacc[mt][nt] = __builtin_amdgcn_mfma_f32_16x16x32_bf16(av[kt][mt], vv, oacc[mt][nt], 0, 0, 0);
      }
#pragma unroll
    for (int mt = 0; mt < 4; ++mt)
#pragma unroll
      for (int r = 0; r < 4; ++r) {
        const int i = mt * 16 + l4 * 4 + r;
#pragma unroll
        for (int nt = 0; nt < 4; ++nt) {
          const float v = oacc[mt][nt][r];
          ob[(size_t)(row0 + i) * 4096 + (c0 + nt * 16 + l15)] = __float2bfloat16(v);
          rs[mt][r] += v * v;
        }
      }
  }

#pragma unroll
  for (int mt = 0; mt < 4; ++mt)
#pragma unroll
    for (int r = 0; r < 4; ++r) {
      float v = rs[mt][r];
      v += __shfl_xor(v, 1); v += __shfl_xor(v, 2);
      v += __shfl_xor(v, 4); v += __shfl_xor(v, 8);
      if (l15 == 0) atomicAdd(&rowsq[mt * 16 + l4 * 4 + r], v);
    }
  __syncthreads();
  if (tid < 64)
    atomicAdd(&rmssum[row0 + tid], rowsq[tid]);
}

// ---------------------------------------------------------------------------
extern "C" void kernel_launch(void* const* d_in, const int* in_sizes, int n_in,
                              void* d_out, int out_size, void* d_ws, size_t ws_size,
                              hipStream_t stream) {
  const float* x   = (const float*)d_in[0];
  const float* Wq  = (const float*)d_in[1];
  const float* Wk  = (const float*)d_in[2];
  const float* Wog = (const float*)d_in[3];
  const float* Wig = (const float*)d_in[4];
  const float* Wo  = (const float*)d_in[5];
  const float* gnw = (const float*)d_in[6];
  float* out = (float*)d_out;

  char* w = (char*)d_ws;
  auto alloc = [&](size_t bytes) {
    char* p = w;
    w += (bytes + 255) & ~(size_t)255;
    return p;
  };
  bf16*  wqkb   = (bf16*)alloc((size_t)256 * 2048 * 2);
  bf16*  wcomb  = (bf16*)alloc((size_t)2048 * 4096 * 2);   // [Wog | Wig]
  bf16*  wob    = (bf16*)alloc((size_t)2048 * 2048 * 2);
  bf16*  acomb  = (bf16*)alloc((size_t)8192 * 4096 * 2);   // [o | x] per row
  bf16*  xbT    = (bf16*)alloc((size_t)8192 * 2048 * 2);
  float* logits = (float*)alloc((size_t)2 * 8192 * 256 * 4);  // 2 split-K partials
  bf16*  qbuf   = (bf16*)alloc((size_t)8192 * 128 * 2);
  bf16*  kbuf   = (bf16*)alloc((size_t)8192 * 128 * 2);
  float* gfbuf  = (float*)alloc((size_t)8192 * 128 * 4);
  float* rmsbuf = (float*)alloc((size_t)8192 * 4);
  bf16*  gatedb = xbT;  // xbT dead after gla_kernel -> reuse for gated

  // weights -> bf16
  cvt_bf16_kernel<<<dim3((65536 + 255) / 256), 256, 0, stream>>>(Wq, wqkb, 65536);
  cvt_bf16_kernel<<<dim3((65536 + 255) / 256), 256, 0, stream>>>(Wk, wqkb + 262144, 65536);
  cvt_bf16_strided<<<dim3((1048576 + 255) / 256), 256, 0, stream>>>(Wog, wcomb, 1048576);
  cvt_bf16_strided<<<dim3((1048576 + 255) / 256), 256, 0, stream>>>(Wig, wcomb + 2048, 1048576);
  cvt_bf16_kernel<<<dim3((1048576 + 255) / 256), 256, 0, stream>>>(Wo, wob, 1048576);

  // x -> acomb[:, 2048:4096] + xbT
  convert_x_kernel<<<dim3(64, 32, 2), 256, 0, stream>>>(x, acomb, xbT);

  // logits partials = x @ [Wq;Wk]^T, split-K over z (256 blocks total)
  gemm_logits<<<dim3(64, 2, 2), 256, 0, stream>>>(
      acomb + 2048, wqkb, logits, 4096, 2048, 256, 1024);

  // q/k/gf from summed partials (+ rms accumulator zero)
  qk_post_kernel<<<dim3(2048), 256, 0, stream>>>(
      logits, logits + (size_t)8192 * 256, qbuf, kbuf, gfbuf, rmsbuf);

  // GLA -> o (bf16, into acomb[:, 0:2048]) + rms partial sums
  gla_kernel<<<dim3(64, 2, 2), 256, 0, stream>>>(qbuf, kbuf, gfbuf, xbT, acomb, rmsbuf);

  // go = [o|x] @ [Wog|Wig]^T (K=4096); gated = RMSNorm(o)*g * swish(go)
  gemm256<1><<<dim3(256), 512, 0, stream>>>(
      acomb, wcomb, nullptr, gatedb, acomb, rmsbuf, gnw, 2048, 4096, 4096);

  // out = gated @ Wo^T
  gemm256<2><<<dim3(256), 512, 0, stream>>>(
      gatedb, wob, out, nullptr, nullptr, nullptr, nullptr, 2048, 2048, 2048);

  (void)in_sizes; (void)n_in; (void)out_size; (void)ws_size;
}